// Round 4
// baseline (798.687 us; speedup 1.0000x reference)
//
#include <hip/hip_runtime.h>
#include <stddef.h>

// ---------------------------------------------------------------------------
// Problem constants
// ---------------------------------------------------------------------------
#define HH 384
#define WW 384
#define CC 200
#define NN 147456      // HH*WW
#define EE 1179648
#define HIDE 128
#define COUT 64
#define NCLS 16
#define BN_EPS 1e-5f

// Replicated stat accumulators: R replicas of 512 floats per slot.
#define SREP 16
#define SLOTF (512 * SREP)
#define DBINS 64

using u16 = unsigned short;
typedef __attribute__((ext_vector_type(8))) short short8;
typedef __attribute__((ext_vector_type(4))) float float4v;

__device__ __forceinline__ float b2f(u16 u) {
    union { unsigned int i; float f; } v; v.i = ((unsigned int)u) << 16; return v.f;
}
__device__ __forceinline__ u16 f2b(float f) {
    union { float f; unsigned int i; } v; v.f = f;
    unsigned int x = v.i;
    unsigned int r = (x + 0x7fffu + ((x >> 16) & 1u)) >> 16;   // RNE
    return (u16)r;
}
__device__ __forceinline__ float lrelu(float v) { return v > 0.f ? v : 0.01f * v; }

// ---------------------------------------------------------------------------
// Dtype sniffer: flag=1 means inputs are float32.
// ---------------------------------------------------------------------------
__global__ void sniff(const u16* __restrict__ x, int* __restrict__ flag) {
    __shared__ int cntS;
    if (threadIdx.x == 0) cntS = 0;
    __syncthreads();
    int c = 0;
    for (int i = 0; i < 8; i++) {
        u16 h = x[threadIdx.x * 8 + i];
        int hb = (h >> 8) & 0x7F;
        if (hb >= 0x3C && hb <= 0x41) c++;
    }
    atomicAdd(&cntS, c);
    __syncthreads();
    if (threadIdx.x == 0) *flag = (cntS < 1536) ? 1 : 0;
}

// ---------------------------------------------------------------------------
// Convert all float params into a bf16 arena (copy if already bf16).
// ---------------------------------------------------------------------------
#define NPAR 27
struct PConv { const void* src[NPAR]; int n[NPAR]; int off[NPAR]; };

__global__ void convert_params(PConv pc, const int* __restrict__ flag,
                               u16* __restrict__ dst) {
    int b = blockIdx.x;
    int n = pc.n[b];
    const void* s = pc.src[b];
    u16* d = dst + pc.off[b];
    int isf = *flag;
    if (isf) {
        const float* sf = (const float*)s;
        for (int i = threadIdx.x; i < n; i += 256) d[i] = f2b(sf[i]);
    } else {
        const u16* sh = (const u16*)s;
        for (int i = threadIdx.x; i < n; i += 256) d[i] = sh[i];
    }
}

// ---------------------------------------------------------------------------
// stats200: LDS-staged column stats of X[N,200].  grid 1152 x 256.
// Atomics go to replica (blockIdx & (SREP-1)) to cut same-address chains.
// ---------------------------------------------------------------------------
__global__ __launch_bounds__(256) void stats200(const void* __restrict__ X,
                                                const int* __restrict__ flag,
                                                float* __restrict__ arena) {
    __shared__ __align__(16) u16 s[128 * 200];   // 51200 B
    int t = threadIdx.x;
    int r0 = blockIdx.x * 128;
    if (*flag) {
        const float* Xf = (const float*)X;
        for (int i = t; i < 128 * 25; i += 256) {
            int r = i / 25, kc = i - r * 25;
            const float* p = Xf + (size_t)(r0 + r) * CC + kc * 8;
            float4v a = *(const float4v*)p;
            float4v b = *(const float4v*)(p + 4);
            short8 v;
            #pragma unroll
            for (int j = 0; j < 4; j++) { v[j] = (short)f2b(a[j]); v[4 + j] = (short)f2b(b[j]); }
            *(short8*)&s[r * 200 + kc * 8] = v;
        }
    } else {
        const u16* Xh = (const u16*)X;
        for (int i = t; i < 128 * 25; i += 256) {
            int r = i / 25, kc = i - r * 25;
            *(short8*)&s[r * 200 + kc * 8] =
                *(const short8*)(Xh + (size_t)(r0 + r) * CC + kc * 8);
        }
    }
    __syncthreads();
    if (t < CC) {
        float sum = 0.f, sq = 0.f;
        for (int r = 0; r < 128; r++) {
            float v = b2f(s[r * 200 + t]);
            sum += v; sq += v * v;
        }
        float* rep = arena + (blockIdx.x & (SREP - 1)) * 512;
        atomicAdd(&rep[t], sum);
        atomicAdd(&rep[256 + t], sq);
    }
}

// ---------------------------------------------------------------------------
// fold_bn v3: sums SREP replicas of the stat slot, then folds BN into W.
// grid = ceil(O/4) blocks, 4 wave-groups each.
// ---------------------------------------------------------------------------
template<int K, int KPAD, int O>
__global__ __launch_bounds__(256) void fold_bn(
        const float* __restrict__ arena, float invN,
        const u16* __restrict__ bng, const u16* __restrict__ bnb,
        const u16* __restrict__ Wsrc, const u16* __restrict__ extrab,
        u16* __restrict__ WT, float* __restrict__ cb) {
    __shared__ float aS[KPAD], sS[KPAD];
    int t = threadIdx.x;
    if (t < KPAD) {
        float a = 0.f, sh = 0.f;
        if (t < K) {
            float sum = 0.f, sq = 0.f;
            #pragma unroll
            for (int r = 0; r < SREP; r++) {
                sum += arena[r * 512 + t];
                sq  += arena[r * 512 + 256 + t];
            }
            float m = sum * invN;
            float var = fmaxf(sq * invN - m * m, 0.f);
            a = b2f(bng[t]) * rsqrtf(var + BN_EPS);
            sh = b2f(bnb[t]) - m * a;
        }
        aS[t] = a; sS[t] = sh;
    }
    __syncthreads();
    int g = t >> 6, l = t & 63;
    int o = blockIdx.x * 4 + g;
    if (o < O) {
        float c = 0.f;
        #pragma unroll
        for (int k = l; k < KPAD; k += 64) {
            float w = (k < K) ? b2f(Wsrc[k * O + o]) : 0.f;
            c += sS[k] * w;
            WT[o * KPAD + k] = f2b(aS[k] * w);
        }
        #pragma unroll
        for (int s = 32; s >= 1; s >>= 1) c += __shfl_down(c, s);
        if (l == 0) cb[o] = c + (extrab ? b2f(extrab[o]) : 0.f);
    }
}

// ---------------------------------------------------------------------------
// MFMA GEMM v4: 64 rows/block, 4 waves, wave w owns ALL 4 row-fragments x
// (O/64) column tiles.
//
// Epilogues:
//   SCALE=false: v = acc + cb  (+leaky if LEAKY)
//   SCALE=true : v = (acc*s1[row] + cb) * s2[row]
// STATS=1: column sum/sumsq of output into stA (replicated slots)
// STATS=2: STATS=1 on stA PLUS per-row L2 invnorm (-> invn) and column stats
//          of v*invnorm into stB.
// DUAL (O=192): cols 0-127 use SCALE epilogue -> out (stride 128);
//               cols 128-191 use plain+leaky -> out2 (stride 64).
// ---------------------------------------------------------------------------
template<int KT, int KSRC, int O, bool LEAKY, bool SCALE, int STATS, bool DUAL>
__global__ __launch_bounds__(256) void gemm_mfma(
        const void* __restrict__ Ap, const u16* __restrict__ WT,
        const float* __restrict__ cb, const float* __restrict__ s1,
        const float* __restrict__ s2, const int* __restrict__ f32p,
        u16* __restrict__ out, float* __restrict__ stA,
        float* __restrict__ stB, float* __restrict__ invn,
        u16* __restrict__ out2) {
    constexpr int KPAD = KT * 32;
    constexpr int LDA = KPAD + 8;
    constexpr int CHR = KPAD / 8;
    constexpr int CHD = KSRC / 8;
    constexpr int NCT = O / 16;
    constexpr int CPW = NCT / 4;          // column tiles per wave
    __shared__ __align__(16) u16 As[64 * LDA];
    __shared__ float rS[4][64];           // per-wave row-ssq partials (STATS==2)
    __shared__ float invS[64];
    __shared__ float sS1[64], sS2[64];
    int tid = threadIdx.x;
    int row0 = blockIdx.x * 64;

    int isf = f32p ? *f32p : 0;
    if (isf) {
        const float* A = (const float*)Ap;
        for (int i = tid; i < 64 * CHR; i += 256) {
            int r = i / CHR, kc = i - r * CHR;
            short8 v = {0, 0, 0, 0, 0, 0, 0, 0};
            if (kc < CHD) {
                const float* p = A + (size_t)(row0 + r) * KSRC + kc * 8;
                float4v a = *(const float4v*)p;
                float4v b = *(const float4v*)(p + 4);
                #pragma unroll
                for (int j = 0; j < 4; j++) { v[j] = (short)f2b(a[j]); v[4 + j] = (short)f2b(b[j]); }
            }
            *(short8*)&As[r * LDA + kc * 8] = v;
        }
    } else {
        const u16* A = (const u16*)Ap;
        for (int i = tid; i < 64 * CHR; i += 256) {
            int r = i / CHR, kc = i - r * CHR;
            short8 v = {0, 0, 0, 0, 0, 0, 0, 0};
            if (kc < CHD)
                v = *(const short8*)(A + (size_t)(row0 + r) * KSRC + kc * 8);
            *(short8*)&As[r * LDA + kc * 8] = v;
        }
    }
    if (SCALE && tid < 64) { sS1[tid] = s1[row0 + tid]; sS2[tid] = s2[row0 + tid]; }
    __syncthreads();

    int w = tid >> 6, lane = tid & 63, m = lane & 15, q = lane >> 4;
    float4v acc[4][CPW];
    #pragma unroll
    for (int mf = 0; mf < 4; mf++)
        #pragma unroll
        for (int cp = 0; cp < CPW; cp++)
            acc[mf][cp] = (float4v){0.f, 0.f, 0.f, 0.f};

    const u16* Abp = &As[m * LDA + q * 8];
    const u16* Bbp = WT + (size_t)((w * CPW) * 16 + m) * KPAD + q * 8;

    #pragma unroll
    for (int kt = 0; kt < KT; kt++) {
        short8 af[4];
        #pragma unroll
        for (int mf = 0; mf < 4; mf++)
            af[mf] = *(const short8*)(Abp + mf * 16 * LDA + kt * 32);
        #pragma unroll
        for (int cp = 0; cp < CPW; cp++) {
            short8 bf = *(const short8*)(Bbp + (size_t)cp * 16 * KPAD + kt * 32);
            #pragma unroll
            for (int mf = 0; mf < 4; mf++)
                acc[mf][cp] = __builtin_amdgcn_mfma_f32_16x16x32_bf16(
                    af[mf], bf, acc[mf][cp], 0, 0, 0);
        }
    }

    // ---- epilogue: apply, store, keep fp32 values in acc for stats ----
    float rp[4][4] = {};
    #pragma unroll
    for (int cp = 0; cp < CPW; cp++) {
        int ct = w * CPW + cp;
        int col = ct * 16 + m;
        float cbv = cb[col];
        #pragma unroll
        for (int mf = 0; mf < 4; mf++) {
            #pragma unroll
            for (int r = 0; r < 4; r++) {
                int rl = mf * 16 + q * 4 + r;
                float x = acc[mf][cp][r];
                if constexpr (DUAL) {
                    if (ct < 8) {
                        x = (x * sS1[rl] + cbv) * sS2[rl];
                        out[(size_t)(row0 + rl) * 128 + col] = f2b(x);
                    } else {
                        x = lrelu(x + cbv);
                        out2[(size_t)(row0 + rl) * 64 + (col - 128)] = f2b(x);
                    }
                } else {
                    if constexpr (SCALE) x = (x * sS1[rl] + cbv) * sS2[rl];
                    else                 x += cbv;
                    if constexpr (LEAKY) x = lrelu(x);
                    out[(size_t)(row0 + rl) * O + col] = f2b(x);
                }
                acc[mf][cp][r] = x;
                if constexpr (STATS == 2) rp[mf][r] += x * x;
            }
        }
    }

    if constexpr (STATS == 2) {
        // row ssq: reduce over the 16 m-lanes (wave holds CPW*16 cols)
        #pragma unroll
        for (int mf = 0; mf < 4; mf++) {
            #pragma unroll
            for (int r = 0; r < 4; r++) {
                float v = rp[mf][r];
                v += __shfl_xor(v, 1); v += __shfl_xor(v, 2);
                v += __shfl_xor(v, 4); v += __shfl_xor(v, 8);
                if (m == 0) rS[w][mf * 16 + q * 4 + r] = v;
            }
        }
        __syncthreads();
        if (tid < 64) {
            float ss = rS[0][tid] + rS[1][tid] + rS[2][tid] + rS[3][tid];
            float inv = 1.0f / fmaxf(sqrtf(ss), 1e-12f);
            invS[tid] = inv;
            invn[row0 + tid] = inv;
        }
        __syncthreads();
    }

    if constexpr (STATS >= 1) {
        float* stAr = stA + (blockIdx.x & (SREP - 1)) * 512;
        float* stBr = (STATS == 2) ? stB + (blockIdx.x & (SREP - 1)) * 512 : nullptr;
        #pragma unroll
        for (int cp = 0; cp < CPW; cp++) {
            int col = (w * CPW + cp) * 16 + m;
            float cs = 0.f, cq = 0.f, ns = 0.f, nq = 0.f;
            #pragma unroll
            for (int mf = 0; mf < 4; mf++) {
                #pragma unroll
                for (int r = 0; r < 4; r++) {
                    float x = acc[mf][cp][r];
                    cs += x; cq += x * x;
                    if constexpr (STATS == 2) {
                        float nv = x * invS[mf * 16 + q * 4 + r];
                        ns += nv; nq += nv * nv;
                    }
                }
            }
            cs += __shfl_xor(cs, 16); cs += __shfl_xor(cs, 32);
            cq += __shfl_xor(cq, 16); cq += __shfl_xor(cq, 32);
            if constexpr (STATS == 2) {
                ns += __shfl_xor(ns, 16); ns += __shfl_xor(ns, 32);
                nq += __shfl_xor(nq, 16); nq += __shfl_xor(nq, 32);
            }
            if (q == 0) {
                atomicAdd(&stAr[col], cs);
                atomicAdd(&stAr[256 + col], cq);
                if constexpr (STATS == 2) {
                    atomicAdd(&stBr[col], ns);
                    atomicAdd(&stBr[256 + col], nq);
                }
            }
        }
    }
}

// ---------------------------------------------------------------------------
// Edge preprocessing: histogram -> dinv -> exclusive scan -> CSR scatter
// ---------------------------------------------------------------------------
__global__ void hist(const int* __restrict__ dst, int* __restrict__ cnt) {
    int e = blockIdx.x * 256 + threadIdx.x;
    unsigned d = (unsigned)dst[e];
    if (d < (unsigned)NN) atomicAdd(&cnt[d], 1);
}
__global__ void mkdinv(const int* __restrict__ cnt, float* __restrict__ dinv) {
    int i = blockIdx.x * 256 + threadIdx.x;
    int c = cnt[i]; if (c < 0) c = 0;
    dinv[i] = rsqrtf((float)c + 1.0f);     // +1 self loop
}
__global__ void scan_part(const int* __restrict__ cnt, int* __restrict__ bsum) {
    int b = blockIdx.x, t = threadIdx.x;
    int base = b * 1024 + t * 4;
    int s = cnt[base] + cnt[base + 1] + cnt[base + 2] + cnt[base + 3];
    #pragma unroll
    for (int o = 32; o >= 1; o >>= 1) s += __shfl_down(s, o);
    __shared__ int ws4[4];
    if ((t & 63) == 0) ws4[t >> 6] = s;
    __syncthreads();
    if (t == 0) bsum[b] = ws4[0] + ws4[1] + ws4[2] + ws4[3];
}
__global__ void scan_top(const int* __restrict__ bsum, int* __restrict__ boff) {
    if (threadIdx.x == 0) {
        int a = 0;
        for (int i = 0; i < 144; i++) { boff[i] = a; a += bsum[i]; }
    }
}
__global__ void scan_write(const int* __restrict__ cnt, const int* __restrict__ boff,
                           int* __restrict__ offv) {
    int b = blockIdx.x, t = threadIdx.x;
    int base = b * 1024 + t * 4;
    int v0 = cnt[base], v1 = cnt[base + 1], v2 = cnt[base + 2], v3 = cnt[base + 3];
    int ts = v0 + v1 + v2 + v3;
    __shared__ int sc[256];
    sc[t] = ts;
    __syncthreads();
    for (int o = 1; o < 256; o <<= 1) {
        int x = (t >= o) ? sc[t - o] : 0;
        __syncthreads();
        sc[t] += x;
        __syncthreads();
    }
    int excl = boff[b] + sc[t] - ts;
    offv[base] = excl;
    offv[base + 1] = excl + v0;
    offv[base + 2] = excl + v0 + v1;
    offv[base + 3] = excl + v0 + v1 + v2;
    if (b == 143 && t == 255) offv[NN] = excl + ts;
}
__global__ void scatter(const int* __restrict__ src, const int* __restrict__ dst,
                        int* __restrict__ cursor, const int* __restrict__ offv,
                        int* __restrict__ csr) {
    int e = blockIdx.x * 256 + threadIdx.x;
    unsigned d = (unsigned)dst[e];
    if (d >= (unsigned)NN) return;
    int p = atomicAdd(&cursor[d], 1);
    unsigned idx = (unsigned)(offv[d] + p);
    if (idx < (unsigned)EE) csr[idx] = src[e];
}

// ---------------------------------------------------------------------------
// Degree-sorted dst permutation (LPT order, heavy bins first) so the groups
// of a wave process equal-trip-count loops (kills exec-mask divergence).
// ---------------------------------------------------------------------------
__global__ void deg_hist(const int* __restrict__ cnt, int* __restrict__ dbin) {
    __shared__ int h[DBINS];
    int t = threadIdx.x;
    if (t < DBINS) h[t] = 0;
    __syncthreads();
    int i = blockIdx.x * 256 + t;
    int dg = cnt[i]; if (dg < 0) dg = 0; if (dg > DBINS - 1) dg = DBINS - 1;
    atomicAdd(&h[dg], 1);
    __syncthreads();
    if (t < DBINS) atomicAdd(&dbin[t], h[t]);
}
__global__ void deg_scan(const int* __restrict__ dbin, int* __restrict__ dbase) {
    if (threadIdx.x == 0) {
        int a = 0;
        for (int b = DBINS - 1; b >= 0; b--) { dbase[b] = a; a += dbin[b]; }
    }
}
__global__ void deg_scatter(const int* __restrict__ cnt, int* __restrict__ dbase,
                            int* __restrict__ perm) {
    __shared__ int h[DBINS], base[DBINS];
    int t = threadIdx.x;
    if (t < DBINS) h[t] = 0;
    __syncthreads();
    int i = blockIdx.x * 256 + t;
    int dg = cnt[i]; if (dg < 0) dg = 0; if (dg > DBINS - 1) dg = DBINS - 1;
    atomicAdd(&h[dg], 1);
    __syncthreads();
    if (t < DBINS) { base[t] = atomicAdd(&dbase[t], h[t]); h[t] = 0; }
    __syncthreads();
    int lp = atomicAdd(&h[dg], 1);
    perm[base[dg] + lp] = i;
}

// ---------------------------------------------------------------------------
// GCN aggregation (h2 = dinv[row]*h[row] pre-scaled in GEMM epilogue):
// out[d] = leaky( dinv[d] * ( sum_s h2[s] + h2[d] ) + b ),  d = perm[pos]
// 8-deep gather unroll (oct/quad/pair/single); degree-sorted perm keeps the
// wave's groups balanced.  CSR fully initialized by construction.
// STATS=1: fused per-row invnorm + normalized column stats -> stA (replicated).
// ---------------------------------------------------------------------------
template<int O, int STATS, int GRP>
__global__ __launch_bounds__(256) void aggregate(
        const u16* __restrict__ h2, const int* __restrict__ offv,
        const int* __restrict__ csr, const float* __restrict__ dinv,
        const u16* __restrict__ gb, u16* __restrict__ outp,
        float* __restrict__ stA, float* __restrict__ invn,
        const int* __restrict__ perm) {
    constexpr int CH = O / 8;
    constexpr int NPB = 256 / CH;          // nodes per group
    __shared__ float colS[O], colQ[O];
    int t = threadIdx.x;
    if (STATS && t < O) { colS[t] = 0.f; colQ[t] = 0.f; }
    int local = t / CH, c = t % CH;
    size_t cof = (size_t)c * 8;
    const u16* hb = h2 + cof;
    short8 gv = *(const short8*)(gb + cof);
    float sreg[8] = {0.f, 0.f, 0.f, 0.f, 0.f, 0.f, 0.f, 0.f};
    float qreg[8] = {0.f, 0.f, 0.f, 0.f, 0.f, 0.f, 0.f, 0.f};

    #pragma unroll
    for (int g = 0; g < GRP; g++) {
        int pos = blockIdx.x * (NPB * GRP) + g * NPB + local;
        int d = perm[pos];
        float acc[8];
        short8 selfv = *(const short8*)(hb + (size_t)d * O);
        #pragma unroll
        for (int j = 0; j < 8; j++) acc[j] = b2f((u16)selfv[j]);
        int e0 = offv[d], e1 = offv[d + 1];
        if (e0 < 0) e0 = 0;
        if (e1 > EE) e1 = EE;
        int k = e0;
        for (; k + 8 <= e1; k += 8) {
            unsigned i0 = (unsigned)csr[k],     i1 = (unsigned)csr[k + 1];
            unsigned i2 = (unsigned)csr[k + 2], i3 = (unsigned)csr[k + 3];
            unsigned i4 = (unsigned)csr[k + 4], i5 = (unsigned)csr[k + 5];
            unsigned i6 = (unsigned)csr[k + 6], i7 = (unsigned)csr[k + 7];
            short8 v0 = *(const short8*)(hb + (size_t)i0 * O);
            short8 v1 = *(const short8*)(hb + (size_t)i1 * O);
            short8 v2 = *(const short8*)(hb + (size_t)i2 * O);
            short8 v3 = *(const short8*)(hb + (size_t)i3 * O);
            short8 v4 = *(const short8*)(hb + (size_t)i4 * O);
            short8 v5 = *(const short8*)(hb + (size_t)i5 * O);
            short8 v6 = *(const short8*)(hb + (size_t)i6 * O);
            short8 v7 = *(const short8*)(hb + (size_t)i7 * O);
            #pragma unroll
            for (int j = 0; j < 8; j++)
                acc[j] += ((b2f((u16)v0[j]) + b2f((u16)v1[j])) +
                           (b2f((u16)v2[j]) + b2f((u16)v3[j]))) +
                          ((b2f((u16)v4[j]) + b2f((u16)v5[j])) +
                           (b2f((u16)v6[j]) + b2f((u16)v7[j])));
        }
        if (k + 4 <= e1) {
            unsigned i0 = (unsigned)csr[k],     i1 = (unsigned)csr[k + 1];
            unsigned i2 = (unsigned)csr[k + 2], i3 = (unsigned)csr[k + 3];
            short8 v0 = *(const short8*)(hb + (size_t)i0 * O);
            short8 v1 = *(const short8*)(hb + (size_t)i1 * O);
            short8 v2 = *(const short8*)(hb + (size_t)i2 * O);
            short8 v3 = *(const short8*)(hb + (size_t)i3 * O);
            #pragma unroll
            for (int j = 0; j < 8; j++)
                acc[j] += (b2f((u16)v0[j]) + b2f((u16)v1[j])) +
                          (b2f((u16)v2[j]) + b2f((u16)v3[j]));
            k += 4;
        }
        if (k + 2 <= e1) {
            unsigned i0 = (unsigned)csr[k], i1 = (unsigned)csr[k + 1];
            short8 v0 = *(const short8*)(hb + (size_t)i0 * O);
            short8 v1 = *(const short8*)(hb + (size_t)i1 * O);
            #pragma unroll
            for (int j = 0; j < 8; j++)
                acc[j] += b2f((u16)v0[j]) + b2f((u16)v1[j]);
            k += 2;
        }
        if (k < e1) {
            unsigned i0 = (unsigned)csr[k];
            short8 v0 = *(const short8*)(hb + (size_t)i0 * O);
            #pragma unroll
            for (int j = 0; j < 8; j++) acc[j] += b2f((u16)v0[j]);
        }
        float dd = dinv[d];
        float outv[8];
        short8 res;
        #pragma unroll
        for (int j = 0; j < 8; j++) {
            outv[j] = lrelu(dd * acc[j] + b2f((u16)gv[j]));
            res[j] = (short)f2b(outv[j]);
        }
        *(short8*)(outp + (size_t)d * O + cof) = res;

        if constexpr (STATS) {
            float ss = 0.f;
            #pragma unroll
            for (int j = 0; j < 8; j++) ss += outv[j] * outv[j];
            // full row = this 16-lane node group (CH==16)
            ss += __shfl_xor(ss, 1); ss += __shfl_xor(ss, 2);
            ss += __shfl_xor(ss, 4); ss += __shfl_xor(ss, 8);
            float inv = 1.0f / fmaxf(sqrtf(ss), 1e-12f);
            if (c == 0) invn[d] = inv;
            #pragma unroll
            for (int j = 0; j < 8; j++) {
                float nv = outv[j] * inv;
                sreg[j] += nv; qreg[j] += nv * nv;
            }
        }
    }

    if constexpr (STATS) {
        __syncthreads();   // colS/colQ init visible
        #pragma unroll
        for (int j = 0; j < 8; j++) {
            float s = sreg[j];
            s += __shfl_xor(s, 16); s += __shfl_xor(s, 32);
            float qq = qreg[j];
            qq += __shfl_xor(qq, 16); qq += __shfl_xor(qq, 32);
            if ((t & 63) < 16) {
                atomicAdd(&colS[c * 8 + j], s);
                atomicAdd(&colQ[c * 8 + j], qq);
            }
        }
        __syncthreads();
        if (t < O) {
            float* rep = stA + (blockIdx.x & (SREP - 1)) * 512;
            atomicAdd(&rep[t], colS[t]);
            atomicAdd(&rep[256 + t], colQ[t]);
        }
    }
}

// ---------------------------------------------------------------------------
// Fused: depthwise 5x5 (SAME) on c[H,W,64] + concat with g3 -> linear 128->16
// -> softmax.  16x16 pixel tile + 2-halo, pixel-major LDS with stride 72.
// ---------------------------------------------------------------------------
__global__ __launch_bounds__(256) void final_fused(
        const u16* __restrict__ g3, const u16* __restrict__ cpre,
        const u16* __restrict__ dwW, const u16* __restrict__ db,
        const u16* __restrict__ lw, const u16* __restrict__ lb,
        const int* __restrict__ flag, void* __restrict__ outp) {
    __shared__ __align__(16) u16 tile[400 * 72];   // 57600 B
    __shared__ __align__(16) u16 wT[25 * 64];      // [tap][ch]
    __shared__ __align__(16) u16 wL[2048];         // [f][o]
    __shared__ float bDW[64];
    __shared__ float bL[16];
    int t = threadIdx.x;
    int tx = blockIdx.x % 24, ty = blockIdx.x / 24;
    int x0 = tx * 16 - 2, y0 = ty * 16 - 2;
    for (int i = t; i < 1600; i += 256) {
        int f = i / 25, tap = i - f * 25;
        wT[tap * 64 + f] = dwW[i];
    }
    for (int i = t; i < 2048; i += 256) wL[i] = lw[i];
    if (t < 64) bDW[t] = b2f(db[t]);
    if (t < 16) bL[t] = b2f(lb[t]);
    for (int u = t; u < 3200; u += 256) {
        int pix = u >> 3, c8 = u & 7;
        int gy = y0 + pix / 20, gx = x0 + pix % 20;
        short8 v = {0, 0, 0, 0, 0, 0, 0, 0};
        if (gy >= 0 && gy < HH && gx >= 0 && gx < WW)
            v = *(const short8*)(cpre + ((size_t)(gy * WW + gx)) * 64 + c8 * 8);
        *(short8*)&tile[pix * 72 + c8 * 8] = v;
    }
    __syncthreads();

    int px = t & 15, py = t >> 4;
    int node = (ty * 16 + py) * WW + tx * 16 + px;
    float y[16];
    #pragma unroll
    for (int o = 0; o < 16; o++) y[o] = bL[o];

    const u16* g3p = g3 + (size_t)node * 64;
    for (int c8 = 0; c8 < 8; c8++) {
        short8 gvv = *(const short8*)(g3p + c8 * 8);
        #pragma unroll
        for (int j = 0; j < 8; j++) {
            float g = b2f((u16)gvv[j]);
            const short8 w0 = *(const short8*)&wL[(c8 * 8 + j) * 16];
            const short8 w1 = *(const short8*)&wL[(c8 * 8 + j) * 16 + 8];
            #pragma unroll
            for (int o = 0; o < 8; o++) {
                y[o]     += g * b2f((u16)w0[o]);
                y[o + 8] += g * b2f((u16)w1[o]);
            }
        }
    }
    for (int c8 = 0; c8 < 8; c8++) {
        float acc[8] = {0.f, 0.f, 0.f, 0.f, 0.f, 0.f, 0.f, 0.f};
        #pragma unroll
        for (int dy = 0; dy < 5; dy++) {
            int rbase = ((py + dy) * 20 + px) * 72 + c8 * 8;
            #pragma unroll
            for (int dx = 0; dx < 5; dx++) {
                short8 v  = *(const short8*)&tile[rbase + dx * 72];
                short8 wv = *(const short8*)&wT[(dy * 5 + dx) * 64 + c8 * 8];
                #pragma unroll
                for (int j = 0; j < 8; j++)
                    acc[j] += b2f((u16)v[j]) * b2f((u16)wv[j]);
            }
        }
        #pragma unroll
        for (int j = 0; j < 8; j++) {
            float cv = lrelu(acc[j] + bDW[c8 * 8 + j]);
            int f = 64 + c8 * 8 + j;
            const short8 w0 = *(const short8*)&wL[f * 16];
            const short8 w1 = *(const short8*)&wL[f * 16 + 8];
            #pragma unroll
            for (int o = 0; o < 8; o++) {
                y[o]     += cv * b2f((u16)w0[o]);
                y[o + 8] += cv * b2f((u16)w1[o]);
            }
        }
    }
    float mx = y[0];
    #pragma unroll
    for (int o = 1; o < 16; o++) mx = fmaxf(mx, y[o]);
    float sum = 0.f;
    #pragma unroll
    for (int o = 0; o < 16; o++) { y[o] = __expf(y[o] - mx); sum += y[o]; }
    float inv = 1.0f / fmaxf(sum, 1e-30f);
    if (*flag) {
        float* of = (float*)outp;
        #pragma unroll
        for (int o = 0; o < 16; o++) of[(size_t)node * 16 + o] = y[o] * inv;
    } else {
        u16* oh = (u16*)outp;
        #pragma unroll
        for (int o = 0; o < 16; o++) oh[(size_t)node * 16 + o] = f2b(y[o] * inv);
    }
}

// ---------------------------------------------------------------------------
// Host launcher
// ---------------------------------------------------------------------------
extern "C" void kernel_launch(void* const* d_in, const int* in_sizes, int n_in,
                              void* d_out, int out_size, void* d_ws, size_t ws_size,
                              hipStream_t stream) {
    const void* X   = d_in[0];
    const int* EIDX = (const int*)d_in[1];
    const int* esrc = EIDX;
    const int* edst = EIDX + EE;

    char* ws = (char*)d_ws;
    size_t off = 0;
    auto alloc = [&](size_t sz) -> char* {
        size_t szr = (sz + 255) & ~(size_t)255;
        char* p;
        if (off + szr <= ws_size) { p = ws + off; off += szr; }
        else { p = ws; }
        return p;
    };

    int*   dflag   = (int*)alloc(256);
    static const int pidx[NPAR] = {2,3,4,5,6,7,8,9,10,11,12,13,14,
                                   15,16,17,18,19,20,21,22,23,24,25,26,27,28};
    static const int pn[NPAR]   = {200,200,25600,128,128,128,16384,128,
                                   128,128,8192,1600,64,
                                   128,128,16384,128,
                                   128,128,16384,128,
                                   128,128,8192,64,
                                   2048,16};
    u16* parena = (u16*)alloc(100352 * 2);
    PConv pc;
    {
        int po = 0;
        for (int i = 0; i < NPAR; i++) {
            pc.src[i] = d_in[pidx[i]];
            pc.n[i] = pn[i];
            pc.off[i] = po;
            po += (pn[i] + 15) & ~15;
        }
    }
    const u16* DN1G = parena + pc.off[0];
    const u16* DN1B = parena + pc.off[1];
    const u16* DNW1 = parena + pc.off[2];
    const u16* DNB1 = parena + pc.off[3];
    const u16* DN2G = parena + pc.off[4];
    const u16* DN2B = parena + pc.off[5];
    const u16* DNW2 = parena + pc.off[6];
    const u16* DNB2 = parena + pc.off[7];
    const u16* CBNG = parena + pc.off[8];
    const u16* CBNB = parena + pc.off[9];
    const u16* CPW  = parena + pc.off[10];
    const u16* CDW  = parena + pc.off[11];
    const u16* CDB  = parena + pc.off[12];
    const u16* G1G  = parena + pc.off[13];
    const u16* G1B  = parena + pc.off[14];
    const u16* G1W  = parena + pc.off[15];
    const u16* G1BI = parena + pc.off[16];
    const u16* G2G  = parena + pc.off[17];
    const u16* G2B  = parena + pc.off[18];
    const u16* G2W  = parena + pc.off[19];
    const u16* G2BI = parena + pc.off[20];
    const u16* G3G  = parena + pc.off[21];
    const u16* G3B  = parena + pc.off[22];
    const u16* G3W  = parena + pc.off[23];
    const u16* G3BI = parena + pc.off[24];
    const u16* LINW = parena + pc.off[25];
    const u16* LINB = parena + pc.off[26];

    // zero region (contiguous)
    int*   cnt     = (int*)alloc((size_t)NN * 4);
    int*   cursor  = (int*)alloc((size_t)NN * 4);
    float* arena   = (float*)alloc((size_t)6 * SLOTF * 4);
    int*   dbin    = (int*)alloc(DBINS * 4);
    // ---- end zero region ----
    int*   offv    = (int*)alloc((size_t)(NN + 1) * 4);
    int*   bsum    = (int*)alloc(144 * 4);
    int*   boff    = (int*)alloc(144 * 4);
    int*   dbase   = (int*)alloc(DBINS * 4);
    int*   perm    = (int*)alloc((size_t)NN * 4);
    float* dinvp   = (float*)alloc((size_t)NN * 4);
    float* invnorm = (float*)alloc((size_t)NN * 4);
    u16*   W1T     = (u16*)alloc(128 * 224 * 2);
    u16*   W2T     = (u16*)alloc(128 * 128 * 2);
    u16*   WgT     = (u16*)alloc(192 * 128 * 2);   // 192 rows: GCN (128) + CNN pw (64)
    float* cb1     = (float*)alloc(128 * 4);
    float* cb2     = (float*)alloc(128 * 4);
    float* cbg     = (float*)alloc(192 * 4);
    int*   csr     = (int*)alloc((size_t)EE * 4);
    u16*   cbuf    = (u16*)alloc((size_t)NN * 64 * 2);    // CNN pre-dwconv "c"
    u16*   big1    = (u16*)alloc((size_t)NN * 128 * 2);   // h scratch
    u16*   big2    = (u16*)alloc((size_t)NN * 128 * 2);   // clean / g1 / g2 / g3

    const float invN = 1.0f / (float)NN;
    size_t zsz = (size_t)((char*)dbin + 256 - (char*)cnt);
    size_t zcap = ((char*)cnt >= ws && (size_t)((char*)cnt - ws) < ws_size)
                      ? ws_size - (size_t)((char*)cnt - ws) : 0;
    if (zsz > zcap) zsz = zcap;
    hipMemsetAsync(cnt, 0, zsz, stream);

    // --- dtype detection + param conversion ---
    sniff<<<1, 256, 0, stream>>>((const u16*)X, dflag);
    convert_params<<<NPAR, 256, 0, stream>>>(pc, dflag, parena);

    // --- edge preprocessing (CSR) first: dinv needed by GCN gemm epilogues ---
    hist<<<EE / 256, 256, 0, stream>>>(edst, cnt);
    mkdinv<<<NN / 256, 256, 0, stream>>>(cnt, dinvp);
    deg_hist<<<NN / 256, 256, 0, stream>>>(cnt, dbin);
    deg_scan<<<1, 64, 0, stream>>>(dbin, dbase);
    deg_scatter<<<NN / 256, 256, 0, stream>>>(cnt, dbase, perm);
    scan_part<<<144, 256, 0, stream>>>(cnt, bsum);
    scan_top<<<1, 64, 0, stream>>>(bsum, boff);
    scan_write<<<144, 256, 0, stream>>>(cnt, boff, offv);
    scatter<<<EE / 256, 256, 0, stream>>>(esrc, edst, cursor, offv, csr);

    // --- denoise ---
    stats200<<<1152, 256, 0, stream>>>(X, dflag, arena + 0 * SLOTF);
    fold_bn<200, 224, 128><<<32, 256, 0, stream>>>(arena + 0 * SLOTF, invN, DN1G, DN1B, DNW1, DNB1, W1T, cb1);
    // dn1 gemm: fused column stats of big1 -> arena slot 1
    gemm_mfma<7, 200, 128, true, false, 1, false><<<NN / 64, 256, 0, stream>>>(
        X, W1T, cb1, nullptr, nullptr, dflag, big1, arena + 1 * SLOTF, nullptr, nullptr, nullptr);
    fold_bn<128, 128, 128><<<32, 256, 0, stream>>>(arena + 1 * SLOTF, invN, DN2G, DN2B, DNW2, DNB2, W2T, cb2);
    // dn2 gemm: fused clean-stats (slot 2, cnn BN), invnorm, normalized stats (slot 3, g1 BN)
    gemm_mfma<4, 128, 128, true, false, 2, false><<<NN / 64, 256, 0, stream>>>(
        big1, W2T, cb2, nullptr, nullptr, nullptr, big2, arena + 2 * SLOTF, arena + 3 * SLOTF, invnorm, nullptr);

    // --- GCN layer 1 + CNN pointwise fused (both read big2=clean) ---
    fold_bn<128, 128, 128><<<32, 256, 0, stream>>>(arena + 3 * SLOTF, invN, G1G, G1B, G1W, nullptr, WgT, cbg);
    fold_bn<128, 128, 64><<<16, 256, 0, stream>>>(arena + 2 * SLOTF, invN, CBNG, CBNB, CPW, nullptr,
                                                  WgT + 128 * 128, cbg + 128);
    // DUAL gemm: cols 0-127 -> big1 (GCN h2, scale epilogue), cols 128-191 -> cbuf (CNN c, leaky)
    gemm_mfma<4, 128, 192, false, true, 0, true><<<NN / 64, 256, 0, stream>>>(
        big2, WgT, cbg, invnorm, dinvp, nullptr, big1, nullptr, nullptr, nullptr, cbuf);
    // aggregate with fused rowstats (invnorm + normalized col stats -> slot 4)
    aggregate<128, 1, 4><<<NN / 64, 256, 0, stream>>>(
        big1, offv, csr, dinvp, G1BI, big2, arena + 4 * SLOTF, invnorm, perm);

    // --- GCN layer 2 ---
    fold_bn<128, 128, 128><<<32, 256, 0, stream>>>(arena + 4 * SLOTF, invN, G2G, G2B, G2W, nullptr, WgT, cbg);
    gemm_mfma<4, 128, 128, false, true, 0, false><<<NN / 64, 256, 0, stream>>>(
        big2, WgT, cbg, invnorm, dinvp, nullptr, big1, nullptr, nullptr, nullptr, nullptr);
    aggregate<128, 1, 4><<<NN / 64, 256, 0, stream>>>(
        big1, offv, csr, dinvp, G2BI, big2, arena + 5 * SLOTF, invnorm, perm);

    // --- GCN layer 3 (128 -> 64) ---
    fold_bn<128, 128, 64><<<16, 256, 0, stream>>>(arena + 5 * SLOTF, invN, G3G, G3B, G3W, nullptr, WgT, cbg);
    gemm_mfma<4, 128, 64, false, true, 0, false><<<NN / 64, 256, 0, stream>>>(
        big2, WgT, cbg, invnorm, dinvp, nullptr, big1, nullptr, nullptr, nullptr, nullptr);
    aggregate<64, 0, 1><<<NN / 32, 256, 0, stream>>>(
        big1, offv, csr, dinvp, G3BI, big2, nullptr, nullptr, perm);

    // --- fused dwconv + final linear + softmax ---
    final_fused<<<576, 256, 0, stream>>>(big2, cbuf, CDW, CDB, LINW, LINB, dflag, d_out);

    (void)in_sizes; (void)n_in; (void)out_size;
}

// Round 5
// 760.059 us; speedup vs baseline: 1.0508x; 1.0508x over previous
//
#include <hip/hip_runtime.h>
#include <stddef.h>

// ---------------------------------------------------------------------------
// Problem constants
// ---------------------------------------------------------------------------
#define HH 384
#define WW 384
#define CC 200
#define NN 147456      // HH*WW
#define EE 1179648
#define HIDE 128
#define COUT 64
#define NCLS 16
#define BN_EPS 1e-5f

// Replicated stat accumulators: R replicas of 512 floats per slot.
#define SREP 16
#define SLOTF (512 * SREP)
#define DBINS 64

// Bucketed CSR build
#define NBKT 72        // buckets of 2048 nodes (dst >> 11); 72*2048 = NN
#define NPBK 288       // partition blocks
#define EPB  4096      // edges per partition block; 288*4096 = EE

using u16 = unsigned short;
typedef __attribute__((ext_vector_type(8))) short short8;
typedef __attribute__((ext_vector_type(4))) float float4v;

__device__ __forceinline__ float b2f(u16 u) {
    union { unsigned int i; float f; } v; v.i = ((unsigned int)u) << 16; return v.f;
}
__device__ __forceinline__ u16 f2b(float f) {
    union { float f; unsigned int i; } v; v.f = f;
    unsigned int x = v.i;
    unsigned int r = (x + 0x7fffu + ((x >> 16) & 1u)) >> 16;   // RNE
    return (u16)r;
}
__device__ __forceinline__ float lrelu(float v) { return v > 0.f ? v : 0.01f * v; }

// ---------------------------------------------------------------------------
// Dtype sniffer: flag=1 means inputs are float32.
// ---------------------------------------------------------------------------
__global__ void sniff(const u16* __restrict__ x, int* __restrict__ flag) {
    __shared__ int cntS;
    if (threadIdx.x == 0) cntS = 0;
    __syncthreads();
    int c = 0;
    for (int i = 0; i < 8; i++) {
        u16 h = x[threadIdx.x * 8 + i];
        int hb = (h >> 8) & 0x7F;
        if (hb >= 0x3C && hb <= 0x41) c++;
    }
    atomicAdd(&cntS, c);
    __syncthreads();
    if (threadIdx.x == 0) *flag = (cntS < 1536) ? 1 : 0;
}

// ---------------------------------------------------------------------------
// Convert all float params into a bf16 arena (copy if already bf16).
// ---------------------------------------------------------------------------
#define NPAR 27
struct PConv { const void* src[NPAR]; int n[NPAR]; int off[NPAR]; };

__global__ void convert_params(PConv pc, const int* __restrict__ flag,
                               u16* __restrict__ dst) {
    int b = blockIdx.x;
    int n = pc.n[b];
    const void* s = pc.src[b];
    u16* d = dst + pc.off[b];
    int isf = *flag;
    if (isf) {
        const float* sf = (const float*)s;
        for (int i = threadIdx.x; i < n; i += 256) d[i] = f2b(sf[i]);
    } else {
        const u16* sh = (const u16*)s;
        for (int i = threadIdx.x; i < n; i += 256) d[i] = sh[i];
    }
}

// ---------------------------------------------------------------------------
// stats200: LDS-staged column stats of X[N,200].  grid 1152 x 256.
// ---------------------------------------------------------------------------
__global__ __launch_bounds__(256) void stats200(const void* __restrict__ X,
                                                const int* __restrict__ flag,
                                                float* __restrict__ arena) {
    __shared__ __align__(16) u16 s[128 * 200];   // 51200 B
    int t = threadIdx.x;
    int r0 = blockIdx.x * 128;
    if (*flag) {
        const float* Xf = (const float*)X;
        for (int i = t; i < 128 * 25; i += 256) {
            int r = i / 25, kc = i - r * 25;
            const float* p = Xf + (size_t)(r0 + r) * CC + kc * 8;
            float4v a = *(const float4v*)p;
            float4v b = *(const float4v*)(p + 4);
            short8 v;
            #pragma unroll
            for (int j = 0; j < 4; j++) { v[j] = (short)f2b(a[j]); v[4 + j] = (short)f2b(b[j]); }
            *(short8*)&s[r * 200 + kc * 8] = v;
        }
    } else {
        const u16* Xh = (const u16*)X;
        for (int i = t; i < 128 * 25; i += 256) {
            int r = i / 25, kc = i - r * 25;
            *(short8*)&s[r * 200 + kc * 8] =
                *(const short8*)(Xh + (size_t)(r0 + r) * CC + kc * 8);
        }
    }
    __syncthreads();
    if (t < CC) {
        float sum = 0.f, sq = 0.f;
        for (int r = 0; r < 128; r++) {
            float v = b2f(s[r * 200 + t]);
            sum += v; sq += v * v;
        }
        float* rep = arena + (blockIdx.x & (SREP - 1)) * 512;
        atomicAdd(&rep[t], sum);
        atomicAdd(&rep[256 + t], sq);
    }
}

// ---------------------------------------------------------------------------
// fold_bn v3: sums SREP replicas of the stat slot, then folds BN into W.
// ---------------------------------------------------------------------------
template<int K, int KPAD, int O>
__global__ __launch_bounds__(256) void fold_bn(
        const float* __restrict__ arena, float invN,
        const u16* __restrict__ bng, const u16* __restrict__ bnb,
        const u16* __restrict__ Wsrc, const u16* __restrict__ extrab,
        u16* __restrict__ WT, float* __restrict__ cb) {
    __shared__ float aS[KPAD], sS[KPAD];
    int t = threadIdx.x;
    if (t < KPAD) {
        float a = 0.f, sh = 0.f;
        if (t < K) {
            float sum = 0.f, sq = 0.f;
            #pragma unroll
            for (int r = 0; r < SREP; r++) {
                sum += arena[r * 512 + t];
                sq  += arena[r * 512 + 256 + t];
            }
            float m = sum * invN;
            float var = fmaxf(sq * invN - m * m, 0.f);
            a = b2f(bng[t]) * rsqrtf(var + BN_EPS);
            sh = b2f(bnb[t]) - m * a;
        }
        aS[t] = a; sS[t] = sh;
    }
    __syncthreads();
    int g = t >> 6, l = t & 63;
    int o = blockIdx.x * 4 + g;
    if (o < O) {
        float c = 0.f;
        #pragma unroll
        for (int k = l; k < KPAD; k += 64) {
            float w = (k < K) ? b2f(Wsrc[k * O + o]) : 0.f;
            c += sS[k] * w;
            WT[o * KPAD + k] = f2b(aS[k] * w);
        }
        #pragma unroll
        for (int s = 32; s >= 1; s >>= 1) c += __shfl_down(c, s);
        if (l == 0) cb[o] = c + (extrab ? b2f(extrab[o]) : 0.f);
    }
}

// ---------------------------------------------------------------------------
// MFMA GEMM v4 (unchanged from round 3)
// ---------------------------------------------------------------------------
template<int KT, int KSRC, int O, bool LEAKY, bool SCALE, int STATS, bool DUAL>
__global__ __launch_bounds__(256) void gemm_mfma(
        const void* __restrict__ Ap, const u16* __restrict__ WT,
        const float* __restrict__ cb, const float* __restrict__ s1,
        const float* __restrict__ s2, const int* __restrict__ f32p,
        u16* __restrict__ out, float* __restrict__ stA,
        float* __restrict__ stB, float* __restrict__ invn,
        u16* __restrict__ out2) {
    constexpr int KPAD = KT * 32;
    constexpr int LDA = KPAD + 8;
    constexpr int CHR = KPAD / 8;
    constexpr int CHD = KSRC / 8;
    constexpr int NCT = O / 16;
    constexpr int CPW = NCT / 4;          // column tiles per wave
    __shared__ __align__(16) u16 As[64 * LDA];
    __shared__ float rS[4][64];           // per-wave row-ssq partials (STATS==2)
    __shared__ float invS[64];
    __shared__ float sS1[64], sS2[64];
    int tid = threadIdx.x;
    int row0 = blockIdx.x * 64;

    int isf = f32p ? *f32p : 0;
    if (isf) {
        const float* A = (const float*)Ap;
        for (int i = tid; i < 64 * CHR; i += 256) {
            int r = i / CHR, kc = i - r * CHR;
            short8 v = {0, 0, 0, 0, 0, 0, 0, 0};
            if (kc < CHD) {
                const float* p = A + (size_t)(row0 + r) * KSRC + kc * 8;
                float4v a = *(const float4v*)p;
                float4v b = *(const float4v*)(p + 4);
                #pragma unroll
                for (int j = 0; j < 4; j++) { v[j] = (short)f2b(a[j]); v[4 + j] = (short)f2b(b[j]); }
            }
            *(short8*)&As[r * LDA + kc * 8] = v;
        }
    } else {
        const u16* A = (const u16*)Ap;
        for (int i = tid; i < 64 * CHR; i += 256) {
            int r = i / CHR, kc = i - r * CHR;
            short8 v = {0, 0, 0, 0, 0, 0, 0, 0};
            if (kc < CHD)
                v = *(const short8*)(A + (size_t)(row0 + r) * KSRC + kc * 8);
            *(short8*)&As[r * LDA + kc * 8] = v;
        }
    }
    if (SCALE && tid < 64) { sS1[tid] = s1[row0 + tid]; sS2[tid] = s2[row0 + tid]; }
    __syncthreads();

    int w = tid >> 6, lane = tid & 63, m = lane & 15, q = lane >> 4;
    float4v acc[4][CPW];
    #pragma unroll
    for (int mf = 0; mf < 4; mf++)
        #pragma unroll
        for (int cp = 0; cp < CPW; cp++)
            acc[mf][cp] = (float4v){0.f, 0.f, 0.f, 0.f};

    const u16* Abp = &As[m * LDA + q * 8];
    const u16* Bbp = WT + (size_t)((w * CPW) * 16 + m) * KPAD + q * 8;

    #pragma unroll
    for (int kt = 0; kt < KT; kt++) {
        short8 af[4];
        #pragma unroll
        for (int mf = 0; mf < 4; mf++)
            af[mf] = *(const short8*)(Abp + mf * 16 * LDA + kt * 32);
        #pragma unroll
        for (int cp = 0; cp < CPW; cp++) {
            short8 bf = *(const short8*)(Bbp + (size_t)cp * 16 * KPAD + kt * 32);
            #pragma unroll
            for (int mf = 0; mf < 4; mf++)
                acc[mf][cp] = __builtin_amdgcn_mfma_f32_16x16x32_bf16(
                    af[mf], bf, acc[mf][cp], 0, 0, 0);
        }
    }

    // ---- epilogue: apply, store, keep fp32 values in acc for stats ----
    float rp[4][4] = {};
    #pragma unroll
    for (int cp = 0; cp < CPW; cp++) {
        int ct = w * CPW + cp;
        int col = ct * 16 + m;
        float cbv = cb[col];
        #pragma unroll
        for (int mf = 0; mf < 4; mf++) {
            #pragma unroll
            for (int r = 0; r < 4; r++) {
                int rl = mf * 16 + q * 4 + r;
                float x = acc[mf][cp][r];
                if constexpr (DUAL) {
                    if (ct < 8) {
                        x = (x * sS1[rl] + cbv) * sS2[rl];
                        out[(size_t)(row0 + rl) * 128 + col] = f2b(x);
                    } else {
                        x = lrelu(x + cbv);
                        out2[(size_t)(row0 + rl) * 64 + (col - 128)] = f2b(x);
                    }
                } else {
                    if constexpr (SCALE) x = (x * sS1[rl] + cbv) * sS2[rl];
                    else                 x += cbv;
                    if constexpr (LEAKY) x = lrelu(x);
                    out[(size_t)(row0 + rl) * O + col] = f2b(x);
                }
                acc[mf][cp][r] = x;
                if constexpr (STATS == 2) rp[mf][r] += x * x;
            }
        }
    }

    if constexpr (STATS == 2) {
        #pragma unroll
        for (int mf = 0; mf < 4; mf++) {
            #pragma unroll
            for (int r = 0; r < 4; r++) {
                float v = rp[mf][r];
                v += __shfl_xor(v, 1); v += __shfl_xor(v, 2);
                v += __shfl_xor(v, 4); v += __shfl_xor(v, 8);
                if (m == 0) rS[w][mf * 16 + q * 4 + r] = v;
            }
        }
        __syncthreads();
        if (tid < 64) {
            float ss = rS[0][tid] + rS[1][tid] + rS[2][tid] + rS[3][tid];
            float inv = 1.0f / fmaxf(sqrtf(ss), 1e-12f);
            invS[tid] = inv;
            invn[row0 + tid] = inv;
        }
        __syncthreads();
    }

    if constexpr (STATS >= 1) {
        float* stAr = stA + (blockIdx.x & (SREP - 1)) * 512;
        float* stBr = (STATS == 2) ? stB + (blockIdx.x & (SREP - 1)) * 512 : nullptr;
        #pragma unroll
        for (int cp = 0; cp < CPW; cp++) {
            int col = (w * CPW + cp) * 16 + m;
            float cs = 0.f, cq = 0.f, ns = 0.f, nq = 0.f;
            #pragma unroll
            for (int mf = 0; mf < 4; mf++) {
                #pragma unroll
                for (int r = 0; r < 4; r++) {
                    float x = acc[mf][cp][r];
                    cs += x; cq += x * x;
                    if constexpr (STATS == 2) {
                        float nv = x * invS[mf * 16 + q * 4 + r];
                        ns += nv; nq += nv * nv;
                    }
                }
            }
            cs += __shfl_xor(cs, 16); cs += __shfl_xor(cs, 32);
            cq += __shfl_xor(cq, 16); cq += __shfl_xor(cq, 32);
            if constexpr (STATS == 2) {
                ns += __shfl_xor(ns, 16); ns += __shfl_xor(ns, 32);
                nq += __shfl_xor(nq, 16); nq += __shfl_xor(nq, 32);
            }
            if (q == 0) {
                atomicAdd(&stAr[col], cs);
                atomicAdd(&stAr[256 + col], cq);
                if constexpr (STATS == 2) {
                    atomicAdd(&stBr[col], ns);
                    atomicAdd(&stBr[256 + col], nq);
                }
            }
        }
    }
}

// ---------------------------------------------------------------------------
// Bucketed CSR build (replaces hist + 3-kernel scan + atomic scatter).
// Bucket = dst >> 11 (72 buckets x 2048 nodes).  No global atomics anywhere;
// csr scatter confined to 64KB L2-resident windows per block.
// ---------------------------------------------------------------------------
__global__ __launch_bounds__(256) void count_bkt(const int* __restrict__ edst,
                                                 int* __restrict__ counts) {
    __shared__ int h[NBKT];
    int t = threadIdx.x, blk = blockIdx.x;
    if (t < NBKT) h[t] = 0;
    __syncthreads();
    int base = blk * EPB;
    for (int i = t; i < EPB; i += 256) {
        unsigned d = (unsigned)edst[base + i];
        if (d < (unsigned)NN) atomicAdd(&h[d >> 11], 1);
    }
    __syncthreads();
    if (t < NBKT) counts[t * NPBK + blk] = h[t];
}

__global__ void scan_bkt(int* __restrict__ counts, int* __restrict__ bbase) {
    __shared__ int bs[NBKT], bb[NBKT];
    int t = threadIdx.x;
    if (t < NBKT) {
        int s = 0;
        for (int i = 0; i < NPBK; i++) s += counts[t * NPBK + i];
        bs[t] = s;
    }
    __syncthreads();
    if (t == 0) {
        int a = 0;
        for (int b = 0; b < NBKT; b++) { bb[b] = a; bbase[b] = a; a += bs[b]; }
        bbase[NBKT] = a;
    }
    __syncthreads();
    if (t < NBKT) {
        int run = bb[t];
        for (int i = 0; i < NPBK; i++) {
            int c = counts[t * NPBK + i];
            counts[t * NPBK + i] = run;
            run += c;
        }
    }
}

__global__ __launch_bounds__(256) void part_bkt(const int* __restrict__ esrc,
                                                const int* __restrict__ edst,
                                                const int* __restrict__ counts,
                                                int2* __restrict__ bpair) {
    __shared__ int cur[NBKT];
    int t = threadIdx.x, blk = blockIdx.x;
    if (t < NBKT) cur[t] = counts[t * NPBK + blk];
    __syncthreads();
    int base = blk * EPB;
    for (int i = t; i < EPB; i += 256) {
        unsigned d = (unsigned)edst[base + i];
        if (d < (unsigned)NN) {
            int pos = atomicAdd(&cur[d >> 11], 1);
            int2 p; p.x = esrc[base + i]; p.y = (int)d;
            bpair[pos] = p;
        }
    }
}

__global__ __launch_bounds__(256) void csr_build(const int2* __restrict__ bpair,
                                                 const int* __restrict__ bbase,
                                                 int* __restrict__ offv,
                                                 int* __restrict__ csr) {
    __shared__ int cntL[2048];
    __shared__ int exL[2048];
    __shared__ int tsum[256];
    int b = blockIdx.x, t = threadIdx.x;
    int e0 = bbase[b], e1 = bbase[b + 1];
    int n0 = b << 11;
    for (int i = t; i < 2048; i += 256) cntL[i] = 0;
    __syncthreads();
    for (int k = e0 + t; k < e1; k += 256) {
        int2 p = bpair[k];
        atomicAdd(&cntL[p.y & 2047], 1);
    }
    __syncthreads();
    // block scan over 2048 (8 per thread)
    int s = 0;
    #pragma unroll
    for (int j = 0; j < 8; j++) s += cntL[t * 8 + j];
    tsum[t] = s;
    __syncthreads();
    for (int o = 1; o < 256; o <<= 1) {
        int x = (t >= o) ? tsum[t - o] : 0;
        __syncthreads();
        tsum[t] += x;
        __syncthreads();
    }
    int run = tsum[t] - s;   // exclusive over threads
    #pragma unroll
    for (int j = 0; j < 8; j++) { int c = cntL[t * 8 + j]; exL[t * 8 + j] = run; run += c; }
    __syncthreads();
    for (int i = t; i < 2048; i += 256) offv[n0 + i] = e0 + exL[i];
    if (b == NBKT - 1 && t == 0) offv[NN] = e1;
    for (int i = t; i < 2048; i += 256) cntL[i] = 0;   // reuse as cursors
    __syncthreads();
    for (int k = e0 + t; k < e1; k += 256) {
        int2 p = bpair[k];
        int l = p.y & 2047;
        int pos = e0 + exL[l] + atomicAdd(&cntL[l], 1);
        csr[pos] = p.x;
    }
}

__global__ void mkdinv2(const int* __restrict__ offv, float* __restrict__ dinv) {
    int i = blockIdx.x * 256 + threadIdx.x;
    dinv[i] = rsqrtf((float)(offv[i + 1] - offv[i]) + 1.0f);   // +1 self loop
}

// ---------------------------------------------------------------------------
// Degree-sorted dst permutation (LPT order, heavy bins first); degree from offv.
// ---------------------------------------------------------------------------
__global__ void deg_hist(const int* __restrict__ offv, int* __restrict__ dbin) {
    __shared__ int h[DBINS];
    int t = threadIdx.x;
    if (t < DBINS) h[t] = 0;
    __syncthreads();
    int i = blockIdx.x * 256 + t;
    int dg = offv[i + 1] - offv[i];
    if (dg < 0) dg = 0; if (dg > DBINS - 1) dg = DBINS - 1;
    atomicAdd(&h[dg], 1);
    __syncthreads();
    if (t < DBINS) atomicAdd(&dbin[t], h[t]);
}
__global__ void deg_scan(const int* __restrict__ dbin, int* __restrict__ dbase) {
    if (threadIdx.x == 0) {
        int a = 0;
        for (int b = DBINS - 1; b >= 0; b--) { dbase[b] = a; a += dbin[b]; }
    }
}
__global__ void deg_scatter(const int* __restrict__ offv, int* __restrict__ dbase,
                            int* __restrict__ perm) {
    __shared__ int h[DBINS], base[DBINS];
    int t = threadIdx.x;
    if (t < DBINS) h[t] = 0;
    __syncthreads();
    int i = blockIdx.x * 256 + t;
    int dg = offv[i + 1] - offv[i];
    if (dg < 0) dg = 0; if (dg > DBINS - 1) dg = DBINS - 1;
    atomicAdd(&h[dg], 1);
    __syncthreads();
    if (t < DBINS) { base[t] = atomicAdd(&dbase[t], h[t]); h[t] = 0; }
    __syncthreads();
    int lp = atomicAdd(&h[dg], 1);
    perm[base[dg] + lp] = i;
}

// ---------------------------------------------------------------------------
// GCN aggregation (unchanged from round 3: perm + 8-deep unroll)
// ---------------------------------------------------------------------------
template<int O, int STATS, int GRP>
__global__ __launch_bounds__(256) void aggregate(
        const u16* __restrict__ h2, const int* __restrict__ offv,
        const int* __restrict__ csr, const float* __restrict__ dinv,
        const u16* __restrict__ gb, u16* __restrict__ outp,
        float* __restrict__ stA, float* __restrict__ invn,
        const int* __restrict__ perm) {
    constexpr int CH = O / 8;
    constexpr int NPB = 256 / CH;          // nodes per group
    __shared__ float colS[O], colQ[O];
    int t = threadIdx.x;
    if (STATS && t < O) { colS[t] = 0.f; colQ[t] = 0.f; }
    int local = t / CH, c = t % CH;
    size_t cof = (size_t)c * 8;
    const u16* hb = h2 + cof;
    short8 gv = *(const short8*)(gb + cof);
    float sreg[8] = {0.f, 0.f, 0.f, 0.f, 0.f, 0.f, 0.f, 0.f};
    float qreg[8] = {0.f, 0.f, 0.f, 0.f, 0.f, 0.f, 0.f, 0.f};

    #pragma unroll
    for (int g = 0; g < GRP; g++) {
        int pos = blockIdx.x * (NPB * GRP) + g * NPB + local;
        int d = perm[pos];
        float acc[8];
        short8 selfv = *(const short8*)(hb + (size_t)d * O);
        #pragma unroll
        for (int j = 0; j < 8; j++) acc[j] = b2f((u16)selfv[j]);
        int e0 = offv[d], e1 = offv[d + 1];
        if (e0 < 0) e0 = 0;
        if (e1 > EE) e1 = EE;
        int k = e0;
        for (; k + 8 <= e1; k += 8) {
            unsigned i0 = (unsigned)csr[k],     i1 = (unsigned)csr[k + 1];
            unsigned i2 = (unsigned)csr[k + 2], i3 = (unsigned)csr[k + 3];
            unsigned i4 = (unsigned)csr[k + 4], i5 = (unsigned)csr[k + 5];
            unsigned i6 = (unsigned)csr[k + 6], i7 = (unsigned)csr[k + 7];
            short8 v0 = *(const short8*)(hb + (size_t)i0 * O);
            short8 v1 = *(const short8*)(hb + (size_t)i1 * O);
            short8 v2 = *(const short8*)(hb + (size_t)i2 * O);
            short8 v3 = *(const short8*)(hb + (size_t)i3 * O);
            short8 v4 = *(const short8*)(hb + (size_t)i4 * O);
            short8 v5 = *(const short8*)(hb + (size_t)i5 * O);
            short8 v6 = *(const short8*)(hb + (size_t)i6 * O);
            short8 v7 = *(const short8*)(hb + (size_t)i7 * O);
            #pragma unroll
            for (int j = 0; j < 8; j++)
                acc[j] += ((b2f((u16)v0[j]) + b2f((u16)v1[j])) +
                           (b2f((u16)v2[j]) + b2f((u16)v3[j]))) +
                          ((b2f((u16)v4[j]) + b2f((u16)v5[j])) +
                           (b2f((u16)v6[j]) + b2f((u16)v7[j])));
        }
        if (k + 4 <= e1) {
            unsigned i0 = (unsigned)csr[k],     i1 = (unsigned)csr[k + 1];
            unsigned i2 = (unsigned)csr[k + 2], i3 = (unsigned)csr[k + 3];
            short8 v0 = *(const short8*)(hb + (size_t)i0 * O);
            short8 v1 = *(const short8*)(hb + (size_t)i1 * O);
            short8 v2 = *(const short8*)(hb + (size_t)i2 * O);
            short8 v3 = *(const short8*)(hb + (size_t)i3 * O);
            #pragma unroll
            for (int j = 0; j < 8; j++)
                acc[j] += (b2f((u16)v0[j]) + b2f((u16)v1[j])) +
                          (b2f((u16)v2[j]) + b2f((u16)v3[j]));
            k += 4;
        }
        if (k + 2 <= e1) {
            unsigned i0 = (unsigned)csr[k], i1 = (unsigned)csr[k + 1];
            short8 v0 = *(const short8*)(hb + (size_t)i0 * O);
            short8 v1 = *(const short8*)(hb + (size_t)i1 * O);
            #pragma unroll
            for (int j = 0; j < 8; j++)
                acc[j] += b2f((u16)v0[j]) + b2f((u16)v1[j]);
            k += 2;
        }
        if (k < e1) {
            unsigned i0 = (unsigned)csr[k];
            short8 v0 = *(const short8*)(hb + (size_t)i0 * O);
            #pragma unroll
            for (int j = 0; j < 8; j++) acc[j] += b2f((u16)v0[j]);
        }
        float dd = dinv[d];
        float outv[8];
        short8 res;
        #pragma unroll
        for (int j = 0; j < 8; j++) {
            outv[j] = lrelu(dd * acc[j] + b2f((u16)gv[j]));
            res[j] = (short)f2b(outv[j]);
        }
        *(short8*)(outp + (size_t)d * O + cof) = res;

        if constexpr (STATS) {
            float ss = 0.f;
            #pragma unroll
            for (int j = 0; j < 8; j++) ss += outv[j] * outv[j];
            ss += __shfl_xor(ss, 1); ss += __shfl_xor(ss, 2);
            ss += __shfl_xor(ss, 4); ss += __shfl_xor(ss, 8);
            float inv = 1.0f / fmaxf(sqrtf(ss), 1e-12f);
            if (c == 0) invn[d] = inv;
            #pragma unroll
            for (int j = 0; j < 8; j++) {
                float nv = outv[j] * inv;
                sreg[j] += nv; qreg[j] += nv * nv;
            }
        }
    }

    if constexpr (STATS) {
        __syncthreads();   // colS/colQ init visible
        #pragma unroll
        for (int j = 0; j < 8; j++) {
            float s = sreg[j];
            s += __shfl_xor(s, 16); s += __shfl_xor(s, 32);
            float qq = qreg[j];
            qq += __shfl_xor(qq, 16); qq += __shfl_xor(qq, 32);
            if ((t & 63) < 16) {
                atomicAdd(&colS[c * 8 + j], s);
                atomicAdd(&colQ[c * 8 + j], qq);
            }
        }
        __syncthreads();
        if (t < O) {
            float* rep = stA + (blockIdx.x & (SREP - 1)) * 512;
            atomicAdd(&rep[t], colS[t]);
            atomicAdd(&rep[256 + t], colQ[t]);
        }
    }
}

// ---------------------------------------------------------------------------
// Fused: depthwise 5x5 (SAME) on c[H,W,64] + concat with g3 -> linear 128->16
// -> softmax.  16x16 pixel tile + 2-halo, pixel-major LDS with stride 72.
// ---------------------------------------------------------------------------
__global__ __launch_bounds__(256) void final_fused(
        const u16* __restrict__ g3, const u16* __restrict__ cpre,
        const u16* __restrict__ dwW, const u16* __restrict__ db,
        const u16* __restrict__ lw, const u16* __restrict__ lb,
        const int* __restrict__ flag, void* __restrict__ outp) {
    __shared__ __align__(16) u16 tile[400 * 72];   // 57600 B
    __shared__ __align__(16) u16 wT[25 * 64];      // [tap][ch]
    __shared__ __align__(16) u16 wL[2048];         // [f][o]
    __shared__ float bDW[64];
    __shared__ float bL[16];
    int t = threadIdx.x;
    int tx = blockIdx.x % 24, ty = blockIdx.x / 24;
    int x0 = tx * 16 - 2, y0 = ty * 16 - 2;
    for (int i = t; i < 1600; i += 256) {
        int f = i / 25, tap = i - f * 25;
        wT[tap * 64 + f] = dwW[i];
    }
    for (int i = t; i < 2048; i += 256) wL[i] = lw[i];
    if (t < 64) bDW[t] = b2f(db[t]);
    if (t < 16) bL[t] = b2f(lb[t]);
    for (int u = t; u < 3200; u += 256) {
        int pix = u >> 3, c8 = u & 7;
        int gy = y0 + pix / 20, gx = x0 + pix % 20;
        short8 v = {0, 0, 0, 0, 0, 0, 0, 0};
        if (gy >= 0 && gy < HH && gx >= 0 && gx < WW)
            v = *(const short8*)(cpre + ((size_t)(gy * WW + gx)) * 64 + c8 * 8);
        *(short8*)&tile[pix * 72 + c8 * 8] = v;
    }
    __syncthreads();

    int px = t & 15, py = t >> 4;
    int node = (ty * 16 + py) * WW + tx * 16 + px;
    float y[16];
    #pragma unroll
    for (int o = 0; o < 16; o++) y[o] = bL[o];

    const u16* g3p = g3 + (size_t)node * 64;
    for (int c8 = 0; c8 < 8; c8++) {
        short8 gvv = *(const short8*)(g3p + c8 * 8);
        #pragma unroll
        for (int j = 0; j < 8; j++) {
            float g = b2f((u16)gvv[j]);
            const short8 w0 = *(const short8*)&wL[(c8 * 8 + j) * 16];
            const short8 w1 = *(const short8*)&wL[(c8 * 8 + j) * 16 + 8];
            #pragma unroll
            for (int o = 0; o < 8; o++) {
                y[o]     += g * b2f((u16)w0[o]);
                y[o + 8] += g * b2f((u16)w1[o]);
            }
        }
    }
    for (int c8 = 0; c8 < 8; c8++) {
        float acc[8] = {0.f, 0.f, 0.f, 0.f, 0.f, 0.f, 0.f, 0.f};
        #pragma unroll
        for (int dy = 0; dy < 5; dy++) {
            int rbase = ((py + dy) * 20 + px) * 72 + c8 * 8;
            #pragma unroll
            for (int dx = 0; dx < 5; dx++) {
                short8 v  = *(const short8*)&tile[rbase + dx * 72];
                short8 wv = *(const short8*)&wT[(dy * 5 + dx) * 64 + c8 * 8];
                #pragma unroll
                for (int j = 0; j < 8; j++)
                    acc[j] += b2f((u16)v[j]) * b2f((u16)wv[j]);
            }
        }
        #pragma unroll
        for (int j = 0; j < 8; j++) {
            float cv = lrelu(acc[j] + bDW[c8 * 8 + j]);
            int f = 64 + c8 * 8 + j;
            const short8 w0 = *(const short8*)&wL[f * 16];
            const short8 w1 = *(const short8*)&wL[f * 16 + 8];
            #pragma unroll
            for (int o = 0; o < 8; o++) {
                y[o]     += cv * b2f((u16)w0[o]);
                y[o + 8] += cv * b2f((u16)w1[o]);
            }
        }
    }
    float mx = y[0];
    #pragma unroll
    for (int o = 1; o < 16; o++) mx = fmaxf(mx, y[o]);
    float sum = 0.f;
    #pragma unroll
    for (int o = 0; o < 16; o++) { y[o] = __expf(y[o] - mx); sum += y[o]; }
    float inv = 1.0f / fmaxf(sum, 1e-30f);
    if (*flag) {
        float* of = (float*)outp;
        #pragma unroll
        for (int o = 0; o < 16; o++) of[(size_t)node * 16 + o] = y[o] * inv;
    } else {
        u16* oh = (u16*)outp;
        #pragma unroll
        for (int o = 0; o < 16; o++) oh[(size_t)node * 16 + o] = f2b(y[o] * inv);
    }
}

// ---------------------------------------------------------------------------
// Host launcher
// ---------------------------------------------------------------------------
extern "C" void kernel_launch(void* const* d_in, const int* in_sizes, int n_in,
                              void* d_out, int out_size, void* d_ws, size_t ws_size,
                              hipStream_t stream) {
    const void* X   = d_in[0];
    const int* EIDX = (const int*)d_in[1];
    const int* esrc = EIDX;
    const int* edst = EIDX + EE;

    char* ws = (char*)d_ws;
    size_t off = 0;
    auto alloc = [&](size_t sz) -> char* {
        size_t szr = (sz + 255) & ~(size_t)255;
        char* p;
        if (off + szr <= ws_size) { p = ws + off; off += szr; }
        else { p = ws; }
        return p;
    };

    int*   dflag   = (int*)alloc(256);
    static const int pidx[NPAR] = {2,3,4,5,6,7,8,9,10,11,12,13,14,
                                   15,16,17,18,19,20,21,22,23,24,25,26,27,28};
    static const int pn[NPAR]   = {200,200,25600,128,128,128,16384,128,
                                   128,128,8192,1600,64,
                                   128,128,16384,128,
                                   128,128,16384,128,
                                   128,128,8192,64,
                                   2048,16};
    u16* parena = (u16*)alloc(100352 * 2);
    PConv pc;
    {
        int po = 0;
        for (int i = 0; i < NPAR; i++) {
            pc.src[i] = d_in[pidx[i]];
            pc.n[i] = pn[i];
            pc.off[i] = po;
            po += (pn[i] + 15) & ~15;
        }
    }
    const u16* DN1G = parena + pc.off[0];
    const u16* DN1B = parena + pc.off[1];
    const u16* DNW1 = parena + pc.off[2];
    const u16* DNB1 = parena + pc.off[3];
    const u16* DN2G = parena + pc.off[4];
    const u16* DN2B = parena + pc.off[5];
    const u16* DNW2 = parena + pc.off[6];
    const u16* DNB2 = parena + pc.off[7];
    const u16* CBNG = parena + pc.off[8];
    const u16* CBNB = parena + pc.off[9];
    const u16* CPW  = parena + pc.off[10];
    const u16* CDW  = parena + pc.off[11];
    const u16* CDB  = parena + pc.off[12];
    const u16* G1G  = parena + pc.off[13];
    const u16* G1B  = parena + pc.off[14];
    const u16* G1W  = parena + pc.off[15];
    const u16* G1BI = parena + pc.off[16];
    const u16* G2G  = parena + pc.off[17];
    const u16* G2B  = parena + pc.off[18];
    const u16* G2W  = parena + pc.off[19];
    const u16* G2BI = parena + pc.off[20];
    const u16* G3G  = parena + pc.off[21];
    const u16* G3B  = parena + pc.off[22];
    const u16* G3W  = parena + pc.off[23];
    const u16* G3BI = parena + pc.off[24];
    const u16* LINW = parena + pc.off[25];
    const u16* LINB = parena + pc.off[26];

    // zero region (contiguous): arena + dbin
    float* arena   = (float*)alloc((size_t)6 * SLOTF * 4);
    int*   dbin    = (int*)alloc(DBINS * 4);
    // ---- end zero region ----
    int*   counts  = (int*)alloc((size_t)NBKT * NPBK * 4);
    int*   bbase   = (int*)alloc((NBKT + 1) * 4);
    int2*  bpair   = (int2*)alloc((size_t)EE * 8);
    int*   offv    = (int*)alloc((size_t)(NN + 1) * 4);
    int*   dbase   = (int*)alloc(DBINS * 4);
    int*   perm    = (int*)alloc((size_t)NN * 4);
    float* dinvp   = (float*)alloc((size_t)NN * 4);
    float* invnorm = (float*)alloc((size_t)NN * 4);
    u16*   W1T     = (u16*)alloc(128 * 224 * 2);
    u16*   W2T     = (u16*)alloc(128 * 128 * 2);
    u16*   WgT     = (u16*)alloc(192 * 128 * 2);   // 192 rows: GCN (128) + CNN pw (64)
    float* cb1     = (float*)alloc(128 * 4);
    float* cb2     = (float*)alloc(128 * 4);
    float* cbg     = (float*)alloc(192 * 4);
    int*   csr     = (int*)alloc((size_t)EE * 4);
    u16*   cbuf    = (u16*)alloc((size_t)NN * 64 * 2);    // CNN pre-dwconv "c"
    u16*   big1    = (u16*)alloc((size_t)NN * 128 * 2);   // h scratch
    u16*   big2    = (u16*)alloc((size_t)NN * 128 * 2);   // clean / g1 / g2 / g3

    const float invN = 1.0f / (float)NN;
    size_t zsz = (size_t)((char*)dbin + 256 - (char*)arena);
    size_t zcap = ((char*)arena >= ws && (size_t)((char*)arena - ws) < ws_size)
                      ? ws_size - (size_t)((char*)arena - ws) : 0;
    if (zsz > zcap) zsz = zcap;
    hipMemsetAsync(arena, 0, zsz, stream);

    // --- dtype detection + param conversion ---
    sniff<<<1, 256, 0, stream>>>((const u16*)X, dflag);
    convert_params<<<NPAR, 256, 0, stream>>>(pc, dflag, parena);

    // --- edge preprocessing: bucketed counting-sort CSR (no global atomics) ---
    count_bkt<<<NPBK, 256, 0, stream>>>(edst, counts);
    scan_bkt<<<1, 128, 0, stream>>>(counts, bbase);
    part_bkt<<<NPBK, 256, 0, stream>>>(esrc, edst, counts, bpair);
    csr_build<<<NBKT, 256, 0, stream>>>(bpair, bbase, offv, csr);
    mkdinv2<<<NN / 256, 256, 0, stream>>>(offv, dinvp);
    deg_hist<<<NN / 256, 256, 0, stream>>>(offv, dbin);
    deg_scan<<<1, 64, 0, stream>>>(dbin, dbase);
    deg_scatter<<<NN / 256, 256, 0, stream>>>(offv, dbase, perm);

    // --- denoise ---
    stats200<<<1152, 256, 0, stream>>>(X, dflag, arena + 0 * SLOTF);
    fold_bn<200, 224, 128><<<32, 256, 0, stream>>>(arena + 0 * SLOTF, invN, DN1G, DN1B, DNW1, DNB1, W1T, cb1);
    // dn1 gemm: fused column stats of big1 -> arena slot 1
    gemm_mfma<7, 200, 128, true, false, 1, false><<<NN / 64, 256, 0, stream>>>(
        X, W1T, cb1, nullptr, nullptr, dflag, big1, arena + 1 * SLOTF, nullptr, nullptr, nullptr);
    fold_bn<128, 128, 128><<<32, 256, 0, stream>>>(arena + 1 * SLOTF, invN, DN2G, DN2B, DNW2, DNB2, W2T, cb2);
    // dn2 gemm: fused clean-stats (slot 2, cnn BN), invnorm, normalized stats (slot 3, g1 BN)
    gemm_mfma<4, 128, 128, true, false, 2, false><<<NN / 64, 256, 0, stream>>>(
        big1, W2T, cb2, nullptr, nullptr, nullptr, big2, arena + 2 * SLOTF, arena + 3 * SLOTF, invnorm, nullptr);

    // --- GCN layer 1 + CNN pointwise fused (both read big2=clean) ---
    fold_bn<128, 128, 128><<<32, 256, 0, stream>>>(arena + 3 * SLOTF, invN, G1G, G1B, G1W, nullptr, WgT, cbg);
    fold_bn<128, 128, 64><<<16, 256, 0, stream>>>(arena + 2 * SLOTF, invN, CBNG, CBNB, CPW, nullptr,
                                                  WgT + 128 * 128, cbg + 128);
    // DUAL gemm: cols 0-127 -> big1 (GCN h2, scale epilogue), cols 128-191 -> cbuf (CNN c, leaky)
    gemm_mfma<4, 128, 192, false, true, 0, true><<<NN / 64, 256, 0, stream>>>(
        big2, WgT, cbg, invnorm, dinvp, nullptr, big1, nullptr, nullptr, nullptr, cbuf);
    // aggregate with fused rowstats (invnorm + normalized col stats -> slot 4)
    aggregate<128, 1, 4><<<NN / 64, 256, 0, stream>>>(
        big1, offv, csr, dinvp, G1BI, big2, arena + 4 * SLOTF, invnorm, perm);

    // --- GCN layer 2 ---
    fold_bn<128, 128, 128><<<32, 256, 0, stream>>>(arena + 4 * SLOTF, invN, G2G, G2B, G2W, nullptr, WgT, cbg);
    gemm_mfma<4, 128, 128, false, true, 0, false><<<NN / 64, 256, 0, stream>>>(
        big2, WgT, cbg, invnorm, dinvp, nullptr, big1, nullptr, nullptr, nullptr, nullptr);
    aggregate<128, 1, 4><<<NN / 64, 256, 0, stream>>>(
        big1, offv, csr, dinvp, G2BI, big2, arena + 5 * SLOTF, invnorm, perm);

    // --- GCN layer 3 (128 -> 64) ---
    fold_bn<128, 128, 64><<<16, 256, 0, stream>>>(arena + 5 * SLOTF, invN, G3G, G3B, G3W, nullptr, WgT, cbg);
    gemm_mfma<4, 128, 64, false, true, 0, false><<<NN / 64, 256, 0, stream>>>(
        big2, WgT, cbg, invnorm, dinvp, nullptr, big1, nullptr, nullptr, nullptr, nullptr);
    aggregate<64, 0, 1><<<NN / 32, 256, 0, stream>>>(
        big1, offv, csr, dinvp, G3BI, big2, nullptr, nullptr, perm);

    // --- fused dwconv + final linear + softmax ---
    final_fused<<<576, 256, 0, stream>>>(big2, cbuf, CDW, CDB, LINW, LINB, dflag, d_out);

    (void)in_sizes; (void)n_in; (void)out_size;
}

// Round 6
// 745.774 us; speedup vs baseline: 1.0710x; 1.0192x over previous
//
#include <hip/hip_runtime.h>
#include <stddef.h>

// ---------------------------------------------------------------------------
// Problem constants
// ---------------------------------------------------------------------------
#define HH 384
#define WW 384
#define CC 200
#define NN 147456      // HH*WW
#define EE 1179648
#define HIDE 128
#define COUT 64
#define NCLS 16
#define BN_EPS 1e-5f

// Replicated stat accumulators: R replicas of 512 floats per slot.
#define SREP 16
#define SLOTF (512 * SREP)
#define DBINS 64

// Bucketed CSR build
#define NBKT 72        // buckets of 2048 nodes (dst >> 11); 72*2048 = NN
#define NPBK 288       // partition blocks
#define EPB  4096      // edges per partition block; 288*4096 = EE

using u16 = unsigned short;
typedef __attribute__((ext_vector_type(8))) short short8;
typedef __attribute__((ext_vector_type(4))) float float4v;

__device__ __forceinline__ float b2f(u16 u) {
    union { unsigned int i; float f; } v; v.i = ((unsigned int)u) << 16; return v.f;
}
__device__ __forceinline__ u16 f2b(float f) {
    union { float f; unsigned int i; } v; v.f = f;
    unsigned int x = v.i;
    unsigned int r = (x + 0x7fffu + ((x >> 16) & 1u)) >> 16;   // RNE
    return (u16)r;
}
__device__ __forceinline__ float lrelu(float v) { return v > 0.f ? v : 0.01f * v; }

// global -> LDS direct DMA, 16B per lane.  LDS dest = uniform base + lane*16.
__device__ __forceinline__ void gload_lds16(const void* g, void* l) {
    __builtin_amdgcn_global_load_lds(
        (const __attribute__((address_space(1))) void*)g,
        (__attribute__((address_space(3))) void*)l, 16, 0, 0);
}

// ---------------------------------------------------------------------------
// Dtype sniffer: flag=1 means inputs are float32.
// ---------------------------------------------------------------------------
__global__ void sniff(const u16* __restrict__ x, int* __restrict__ flag) {
    __shared__ int cntS;
    if (threadIdx.x == 0) cntS = 0;
    __syncthreads();
    int c = 0;
    for (int i = 0; i < 8; i++) {
        u16 h = x[threadIdx.x * 8 + i];
        int hb = (h >> 8) & 0x7F;
        if (hb >= 0x3C && hb <= 0x41) c++;
    }
    atomicAdd(&cntS, c);
    __syncthreads();
    if (threadIdx.x == 0) *flag = (cntS < 1536) ? 1 : 0;
}

// ---------------------------------------------------------------------------
// Convert all float params into a bf16 arena (copy if already bf16).
// ---------------------------------------------------------------------------
#define NPAR 27
struct PConv { const void* src[NPAR]; int n[NPAR]; int off[NPAR]; };

__global__ void convert_params(PConv pc, const int* __restrict__ flag,
                               u16* __restrict__ dst) {
    int b = blockIdx.x;
    int n = pc.n[b];
    const void* s = pc.src[b];
    u16* d = dst + pc.off[b];
    int isf = *flag;
    if (isf) {
        const float* sf = (const float*)s;
        for (int i = threadIdx.x; i < n; i += 256) d[i] = f2b(sf[i]);
    } else {
        const u16* sh = (const u16*)s;
        for (int i = threadIdx.x; i < n; i += 256) d[i] = sh[i];
    }
}

// ---------------------------------------------------------------------------
// stats200: LDS-staged column stats of X[N,200].  grid 1152 x 256.
// ---------------------------------------------------------------------------
__global__ __launch_bounds__(256) void stats200(const void* __restrict__ X,
                                                const int* __restrict__ flag,
                                                float* __restrict__ arena) {
    __shared__ __align__(16) u16 s[128 * 200];   // 51200 B
    int t = threadIdx.x;
    int r0 = blockIdx.x * 128;
    if (*flag) {
        const float* Xf = (const float*)X;
        for (int i = t; i < 128 * 25; i += 256) {
            int r = i / 25, kc = i - r * 25;
            const float* p = Xf + (size_t)(r0 + r) * CC + kc * 8;
            float4v a = *(const float4v*)p;
            float4v b = *(const float4v*)(p + 4);
            short8 v;
            #pragma unroll
            for (int j = 0; j < 4; j++) { v[j] = (short)f2b(a[j]); v[4 + j] = (short)f2b(b[j]); }
            *(short8*)&s[r * 200 + kc * 8] = v;
        }
    } else {
        const u16* Xh = (const u16*)X;
        for (int i = t; i < 128 * 25; i += 256) {
            int r = i / 25, kc = i - r * 25;
            *(short8*)&s[r * 200 + kc * 8] =
                *(const short8*)(Xh + (size_t)(r0 + r) * CC + kc * 8);
        }
    }
    __syncthreads();
    if (t < CC) {
        float sum = 0.f, sq = 0.f;
        for (int r = 0; r < 128; r++) {
            float v = b2f(s[r * 200 + t]);
            sum += v; sq += v * v;
        }
        float* rep = arena + (blockIdx.x & (SREP - 1)) * 512;
        atomicAdd(&rep[t], sum);
        atomicAdd(&rep[256 + t], sq);
    }
}

// ---------------------------------------------------------------------------
// fold_bn v3: sums SREP replicas of the stat slot, then folds BN into W.
// ---------------------------------------------------------------------------
template<int K, int KPAD, int O>
__global__ __launch_bounds__(256) void fold_bn(
        const float* __restrict__ arena, float invN,
        const u16* __restrict__ bng, const u16* __restrict__ bnb,
        const u16* __restrict__ Wsrc, const u16* __restrict__ extrab,
        u16* __restrict__ WT, float* __restrict__ cb) {
    __shared__ float aS[KPAD], sS[KPAD];
    int t = threadIdx.x;
    if (t < KPAD) {
        float a = 0.f, sh = 0.f;
        if (t < K) {
            float sum = 0.f, sq = 0.f;
            #pragma unroll
            for (int r = 0; r < SREP; r++) {
                sum += arena[r * 512 + t];
                sq  += arena[r * 512 + 256 + t];
            }
            float m = sum * invN;
            float var = fmaxf(sq * invN - m * m, 0.f);
            a = b2f(bng[t]) * rsqrtf(var + BN_EPS);
            sh = b2f(bnb[t]) - m * a;
        }
        aS[t] = a; sS[t] = sh;
    }
    __syncthreads();
    int g = t >> 6, l = t & 63;
    int o = blockIdx.x * 4 + g;
    if (o < O) {
        float c = 0.f;
        #pragma unroll
        for (int k = l; k < KPAD; k += 64) {
            float w = (k < K) ? b2f(Wsrc[k * O + o]) : 0.f;
            c += sS[k] * w;
            WT[o * KPAD + k] = f2b(aS[k] * w);
        }
        #pragma unroll
        for (int s = 32; s >= 1; s >>= 1) c += __shfl_down(c, s);
        if (l == 0) cb[o] = c + (extrab ? b2f(extrab[o]) : 0.f);
    }
}

// ---------------------------------------------------------------------------
// MFMA GEMM v5: A-staging via global_load_lds (16B DMA) into a chunk-XOR
// swizzled LDS image: 16B slot s of row r holds global chunk (s ^ (r&7)).
// Swizzle applied on the per-lane GLOBAL address (LDS dest is linear);
// fragment reads use the same XOR -> <=2-way bank aliasing (free).
// f32 input path writes the same swizzled layout manually.
// ---------------------------------------------------------------------------
template<int KT, int KSRC, int O, bool LEAKY, bool SCALE, int STATS, bool DUAL>
__global__ __launch_bounds__(256) void gemm_mfma(
        const void* __restrict__ Ap, const u16* __restrict__ WT,
        const float* __restrict__ cb, const float* __restrict__ s1,
        const float* __restrict__ s2, const int* __restrict__ f32p,
        u16* __restrict__ out, float* __restrict__ stA,
        float* __restrict__ stB, float* __restrict__ invn,
        u16* __restrict__ out2, const u16* __restrict__ zpad) {
    constexpr int KPAD = KT * 32;
    constexpr int CHD = KSRC / 8;               // real 16B chunks per row
    constexpr int ROWCH = ((KT * 4 + 7) / 8) * 8; // padded chunks (mult of 8)
    constexpr int ROWE = ROWCH * 8;             // elems per padded row
    constexpr int LPR = ROWCH;                  // lanes per row (16B each)
    constexpr int RPI = 64 / LPR;               // rows per 1024B DMA instr
    constexpr int NSI = 64 / RPI;               // DMA instrs per block
    constexpr int NCT = O / 16;
    constexpr int CPW = NCT / 4;                // column tiles per wave
    __shared__ __align__(16) u16 As[64 * ROWE];
    __shared__ float rS[4][64];
    __shared__ float invS[64];
    __shared__ float sS1[64], sS2[64];
    int tid = threadIdx.x;
    int row0 = blockIdx.x * 64;

    int isf = f32p ? *f32p : 0;
    if (isf) {
        const float* A = (const float*)Ap;
        for (int i = tid; i < 64 * ROWCH; i += 256) {
            int r = i / ROWCH, slot = i - r * ROWCH;
            int chunk = slot ^ (r & 7);
            short8 v = {0, 0, 0, 0, 0, 0, 0, 0};
            if (chunk < CHD) {
                const float* p = A + (size_t)(row0 + r) * KSRC + chunk * 8;
                float4v a = *(const float4v*)p;
                float4v b = *(const float4v*)(p + 4);
                #pragma unroll
                for (int j = 0; j < 4; j++) { v[j] = (short)f2b(a[j]); v[4 + j] = (short)f2b(b[j]); }
            }
            *(short8*)&As[r * ROWE + slot * 8] = v;
        }
    } else {
        const u16* A = (const u16*)Ap;
        int l = tid & 63, wv = tid >> 6;
        int rl0 = l / LPR, cL = l - rl0 * LPR;
        #pragma unroll
        for (int s = 0; s < NSI / 4; s++) {
            int si = wv + s * 4;
            int rL = si * RPI + rl0;
            int chunk = cL ^ (rL & 7);
            const u16* src = (chunk < CHD)
                ? A + (size_t)(row0 + rL) * KSRC + chunk * 8 : zpad;
            gload_lds16(src, (char*)As + si * 1024);
        }
    }
    if (SCALE && tid < 64) { sS1[tid] = s1[row0 + tid]; sS2[tid] = s2[row0 + tid]; }
    __syncthreads();

    int w = tid >> 6, lane = tid & 63, m = lane & 15, q = lane >> 4;
    float4v acc[4][CPW];
    #pragma unroll
    for (int mf = 0; mf < 4; mf++)
        #pragma unroll
        for (int cp = 0; cp < CPW; cp++)
            acc[mf][cp] = (float4v){0.f, 0.f, 0.f, 0.f};

    const u16* Bbp = WT + (size_t)((w * CPW) * 16 + m) * KPAD + q * 8;

    #pragma unroll
    for (int kt = 0; kt < KT; kt++) {
        short8 af[4];
        int slot = (kt * 4 + q) ^ (m & 7);
        #pragma unroll
        for (int mf = 0; mf < 4; mf++)
            af[mf] = *(const short8*)&As[(size_t)(mf * 16 + m) * ROWE + slot * 8];
        #pragma unroll
        for (int cp = 0; cp < CPW; cp++) {
            short8 bf = *(const short8*)(Bbp + (size_t)cp * 16 * KPAD + kt * 32);
            #pragma unroll
            for (int mf = 0; mf < 4; mf++)
                acc[mf][cp] = __builtin_amdgcn_mfma_f32_16x16x32_bf16(
                    af[mf], bf, acc[mf][cp], 0, 0, 0);
        }
    }

    // ---- epilogue: apply, store, keep fp32 values in acc for stats ----
    float rp[4][4] = {};
    #pragma unroll
    for (int cp = 0; cp < CPW; cp++) {
        int ct = w * CPW + cp;
        int col = ct * 16 + m;
        float cbv = cb[col];
        #pragma unroll
        for (int mf = 0; mf < 4; mf++) {
            #pragma unroll
            for (int r = 0; r < 4; r++) {
                int rl = mf * 16 + q * 4 + r;
                float x = acc[mf][cp][r];
                if constexpr (DUAL) {
                    if (ct < 8) {
                        x = (x * sS1[rl] + cbv) * sS2[rl];
                        out[(size_t)(row0 + rl) * 128 + col] = f2b(x);
                    } else {
                        x = lrelu(x + cbv);
                        out2[(size_t)(row0 + rl) * 64 + (col - 128)] = f2b(x);
                    }
                } else {
                    if constexpr (SCALE) x = (x * sS1[rl] + cbv) * sS2[rl];
                    else                 x += cbv;
                    if constexpr (LEAKY) x = lrelu(x);
                    out[(size_t)(row0 + rl) * O + col] = f2b(x);
                }
                acc[mf][cp][r] = x;
                if constexpr (STATS == 2) rp[mf][r] += x * x;
            }
        }
    }

    if constexpr (STATS == 2) {
        #pragma unroll
        for (int mf = 0; mf < 4; mf++) {
            #pragma unroll
            for (int r = 0; r < 4; r++) {
                float v = rp[mf][r];
                v += __shfl_xor(v, 1); v += __shfl_xor(v, 2);
                v += __shfl_xor(v, 4); v += __shfl_xor(v, 8);
                if (m == 0) rS[w][mf * 16 + q * 4 + r] = v;
            }
        }
        __syncthreads();
        if (tid < 64) {
            float ss = rS[0][tid] + rS[1][tid] + rS[2][tid] + rS[3][tid];
            float inv = 1.0f / fmaxf(sqrtf(ss), 1e-12f);
            invS[tid] = inv;
            invn[row0 + tid] = inv;
        }
        __syncthreads();
    }

    if constexpr (STATS >= 1) {
        float* stAr = stA + (blockIdx.x & (SREP - 1)) * 512;
        float* stBr = (STATS == 2) ? stB + (blockIdx.x & (SREP - 1)) * 512 : nullptr;
        #pragma unroll
        for (int cp = 0; cp < CPW; cp++) {
            int col = (w * CPW + cp) * 16 + m;
            float cs = 0.f, cq = 0.f, ns = 0.f, nq = 0.f;
            #pragma unroll
            for (int mf = 0; mf < 4; mf++) {
                #pragma unroll
                for (int r = 0; r < 4; r++) {
                    float x = acc[mf][cp][r];
                    cs += x; cq += x * x;
                    if constexpr (STATS == 2) {
                        float nv = x * invS[mf * 16 + q * 4 + r];
                        ns += nv; nq += nv * nv;
                    }
                }
            }
            cs += __shfl_xor(cs, 16); cs += __shfl_xor(cs, 32);
            cq += __shfl_xor(cq, 16); cq += __shfl_xor(cq, 32);
            if constexpr (STATS == 2) {
                ns += __shfl_xor(ns, 16); ns += __shfl_xor(ns, 32);
                nq += __shfl_xor(nq, 16); nq += __shfl_xor(nq, 32);
            }
            if (q == 0) {
                atomicAdd(&stAr[col], cs);
                atomicAdd(&stAr[256 + col], cq);
                if constexpr (STATS == 2) {
                    atomicAdd(&stBr[col], ns);
                    atomicAdd(&stBr[256 + col], nq);
                }
            }
        }
    }
}

// ---------------------------------------------------------------------------
// Bucketed CSR build.  Bucket = dst >> 11 (72 buckets x 2048 nodes).
// part_bkt v2: block-local LDS bucket sort -> coalesced bpair writes.
// ---------------------------------------------------------------------------
__global__ __launch_bounds__(256) void count_bkt(const int* __restrict__ edst,
                                                 int* __restrict__ counts) {
    __shared__ int h[NBKT];
    int t = threadIdx.x, blk = blockIdx.x;
    if (t < NBKT) h[t] = 0;
    __syncthreads();
    int base = blk * EPB;
    for (int i = t; i < EPB; i += 256) {
        unsigned d = (unsigned)edst[base + i];
        if (d < (unsigned)NN) atomicAdd(&h[d >> 11], 1);
    }
    __syncthreads();
    if (t < NBKT) counts[t * NPBK + blk] = h[t];
}

__global__ void scan_bkt(int* __restrict__ counts, int* __restrict__ bbase) {
    __shared__ int bs[NBKT], bb[NBKT];
    int t = threadIdx.x;
    if (t < NBKT) {
        int s = 0;
        for (int i = 0; i < NPBK; i++) s += counts[t * NPBK + i];
        bs[t] = s;
    }
    __syncthreads();
    if (t == 0) {
        int a = 0;
        for (int b = 0; b < NBKT; b++) { bb[b] = a; bbase[b] = a; a += bs[b]; }
        bbase[NBKT] = a;
    }
    __syncthreads();
    if (t < NBKT) {
        int run = bb[t];
        for (int i = 0; i < NPBK; i++) {
            int c = counts[t * NPBK + i];
            counts[t * NPBK + i] = run;
            run += c;
        }
    }
}

__global__ __launch_bounds__(256) void part_bkt(const int* __restrict__ esrc,
                                                const int* __restrict__ edst,
                                                const int* __restrict__ counts,
                                                int2* __restrict__ bpair) {
    __shared__ int2 buf[EPB];                // 32 KB
    __shared__ int lcnt[NBKT], lbase[NBKT], gbase[NBKT];
    int t = threadIdx.x, blk = blockIdx.x;
    if (t < NBKT) lcnt[t] = 0;
    __syncthreads();
    int base = blk * EPB;
    int dv[16], sv[16];
    #pragma unroll
    for (int j = 0; j < 16; j++) {
        dv[j] = edst[base + t + j * 256];
        sv[j] = esrc[base + t + j * 256];
        unsigned ud = (unsigned)dv[j];
        if (ud < (unsigned)NN) atomicAdd(&lcnt[ud >> 11], 1);
    }
    __syncthreads();
    if (t == 0) {
        int a = 0;
        for (int b = 0; b < NBKT; b++) { lbase[b] = a; a += lcnt[b]; }
    }
    __syncthreads();
    if (t < NBKT) { gbase[t] = counts[t * NPBK + blk]; lcnt[t] = 0; }
    __syncthreads();
    #pragma unroll
    for (int j = 0; j < 16; j++) {
        unsigned ud = (unsigned)dv[j];
        if (ud < (unsigned)NN) {
            int b = ud >> 11;
            int p = lbase[b] + atomicAdd(&lcnt[b], 1);
            int2 e; e.x = sv[j]; e.y = (int)ud;
            buf[p] = e;
        }
    }
    __syncthreads();
    int tot = lbase[NBKT - 1] + lcnt[NBKT - 1];
    for (int i = t; i < tot; i += 256) {
        int2 p = buf[i];
        int b = ((unsigned)p.y) >> 11;
        bpair[gbase[b] + (i - lbase[b])] = p;
    }
}

__global__ __launch_bounds__(256) void csr_build(const int2* __restrict__ bpair,
                                                 const int* __restrict__ bbase,
                                                 int* __restrict__ offv,
                                                 int* __restrict__ csr) {
    __shared__ int cntL[2048];
    __shared__ int exL[2048];
    __shared__ int tsum[256];
    int b = blockIdx.x, t = threadIdx.x;
    int e0 = bbase[b], e1 = bbase[b + 1];
    int n0 = b << 11;
    for (int i = t; i < 2048; i += 256) cntL[i] = 0;
    __syncthreads();
    for (int k = e0 + t; k < e1; k += 256) {
        int2 p = bpair[k];
        atomicAdd(&cntL[p.y & 2047], 1);
    }
    __syncthreads();
    int s = 0;
    #pragma unroll
    for (int j = 0; j < 8; j++) s += cntL[t * 8 + j];
    tsum[t] = s;
    __syncthreads();
    for (int o = 1; o < 256; o <<= 1) {
        int x = (t >= o) ? tsum[t - o] : 0;
        __syncthreads();
        tsum[t] += x;
        __syncthreads();
    }
    int run = tsum[t] - s;
    #pragma unroll
    for (int j = 0; j < 8; j++) { int c = cntL[t * 8 + j]; exL[t * 8 + j] = run; run += c; }
    __syncthreads();
    for (int i = t; i < 2048; i += 256) offv[n0 + i] = e0 + exL[i];
    if (b == NBKT - 1 && t == 0) offv[NN] = e1;
    for (int i = t; i < 2048; i += 256) cntL[i] = 0;
    __syncthreads();
    for (int k = e0 + t; k < e1; k += 256) {
        int2 p = bpair[k];
        int l = p.y & 2047;
        int pos = e0 + exL[l] + atomicAdd(&cntL[l], 1);
        csr[pos] = p.x;
    }
}

// Fused: dinv + degree histogram (both derive from offv diffs).
__global__ void mkdinv_deghist(const int* __restrict__ offv,
                               float* __restrict__ dinv, int* __restrict__ dbin) {
    __shared__ int h[DBINS];
    int t = threadIdx.x;
    if (t < DBINS) h[t] = 0;
    __syncthreads();
    int i = blockIdx.x * 256 + t;
    int dg = offv[i + 1] - offv[i];
    if (dg < 0) dg = 0;
    dinv[i] = rsqrtf((float)dg + 1.0f);     // +1 self loop
    int dc = dg > DBINS - 1 ? DBINS - 1 : dg;
    atomicAdd(&h[dc], 1);
    __syncthreads();
    if (t < DBINS) atomicAdd(&dbin[t], h[t]);
}
__global__ void deg_scan(const int* __restrict__ dbin, int* __restrict__ dbase) {
    if (threadIdx.x == 0) {
        int a = 0;
        for (int b = DBINS - 1; b >= 0; b--) { dbase[b] = a; a += dbin[b]; }
    }
}
__global__ void deg_scatter(const int* __restrict__ offv, int* __restrict__ dbase,
                            int* __restrict__ perm) {
    __shared__ int h[DBINS], base[DBINS];
    int t = threadIdx.x;
    if (t < DBINS) h[t] = 0;
    __syncthreads();
    int i = blockIdx.x * 256 + t;
    int dg = offv[i + 1] - offv[i];
    if (dg < 0) dg = 0; if (dg > DBINS - 1) dg = DBINS - 1;
    atomicAdd(&h[dg], 1);
    __syncthreads();
    if (t < DBINS) { base[t] = atomicAdd(&dbase[t], h[t]); h[t] = 0; }
    __syncthreads();
    int lp = atomicAdd(&h[dg], 1);
    perm[base[dg] + lp] = i;
}

// ---------------------------------------------------------------------------
// GCN aggregation (unchanged: perm + 8-deep unroll)
// ---------------------------------------------------------------------------
template<int O, int STATS, int GRP>
__global__ __launch_bounds__(256) void aggregate(
        const u16* __restrict__ h2, const int* __restrict__ offv,
        const int* __restrict__ csr, const float* __restrict__ dinv,
        const u16* __restrict__ gb, u16* __restrict__ outp,
        float* __restrict__ stA, float* __restrict__ invn,
        const int* __restrict__ perm) {
    constexpr int CH = O / 8;
    constexpr int NPB = 256 / CH;          // nodes per group
    __shared__ float colS[O], colQ[O];
    int t = threadIdx.x;
    if (STATS && t < O) { colS[t] = 0.f; colQ[t] = 0.f; }
    int local = t / CH, c = t % CH;
    size_t cof = (size_t)c * 8;
    const u16* hb = h2 + cof;
    short8 gv = *(const short8*)(gb + cof);
    float sreg[8] = {0.f, 0.f, 0.f, 0.f, 0.f, 0.f, 0.f, 0.f};
    float qreg[8] = {0.f, 0.f, 0.f, 0.f, 0.f, 0.f, 0.f, 0.f};

    #pragma unroll
    for (int g = 0; g < GRP; g++) {
        int pos = blockIdx.x * (NPB * GRP) + g * NPB + local;
        int d = perm[pos];
        float acc[8];
        short8 selfv = *(const short8*)(hb + (size_t)d * O);
        #pragma unroll
        for (int j = 0; j < 8; j++) acc[j] = b2f((u16)selfv[j]);
        int e0 = offv[d], e1 = offv[d + 1];
        if (e0 < 0) e0 = 0;
        if (e1 > EE) e1 = EE;
        int k = e0;
        for (; k + 8 <= e1; k += 8) {
            unsigned i0 = (unsigned)csr[k],     i1 = (unsigned)csr[k + 1];
            unsigned i2 = (unsigned)csr[k + 2], i3 = (unsigned)csr[k + 3];
            unsigned i4 = (unsigned)csr[k + 4], i5 = (unsigned)csr[k + 5];
            unsigned i6 = (unsigned)csr[k + 6], i7 = (unsigned)csr[k + 7];
            short8 v0 = *(const short8*)(hb + (size_t)i0 * O);
            short8 v1 = *(const short8*)(hb + (size_t)i1 * O);
            short8 v2 = *(const short8*)(hb + (size_t)i2 * O);
            short8 v3 = *(const short8*)(hb + (size_t)i3 * O);
            short8 v4 = *(const short8*)(hb + (size_t)i4 * O);
            short8 v5 = *(const short8*)(hb + (size_t)i5 * O);
            short8 v6 = *(const short8*)(hb + (size_t)i6 * O);
            short8 v7 = *(const short8*)(hb + (size_t)i7 * O);
            #pragma unroll
            for (int j = 0; j < 8; j++)
                acc[j] += ((b2f((u16)v0[j]) + b2f((u16)v1[j])) +
                           (b2f((u16)v2[j]) + b2f((u16)v3[j]))) +
                          ((b2f((u16)v4[j]) + b2f((u16)v5[j])) +
                           (b2f((u16)v6[j]) + b2f((u16)v7[j])));
        }
        if (k + 4 <= e1) {
            unsigned i0 = (unsigned)csr[k],     i1 = (unsigned)csr[k + 1];
            unsigned i2 = (unsigned)csr[k + 2], i3 = (unsigned)csr[k + 3];
            short8 v0 = *(const short8*)(hb + (size_t)i0 * O);
            short8 v1 = *(const short8*)(hb + (size_t)i1 * O);
            short8 v2 = *(const short8*)(hb + (size_t)i2 * O);
            short8 v3 = *(const short8*)(hb + (size_t)i3 * O);
            #pragma unroll
            for (int j = 0; j < 8; j++)
                acc[j] += (b2f((u16)v0[j]) + b2f((u16)v1[j])) +
                          (b2f((u16)v2[j]) + b2f((u16)v3[j]));
            k += 4;
        }
        if (k + 2 <= e1) {
            unsigned i0 = (unsigned)csr[k], i1 = (unsigned)csr[k + 1];
            short8 v0 = *(const short8*)(hb + (size_t)i0 * O);
            short8 v1 = *(const short8*)(hb + (size_t)i1 * O);
            #pragma unroll
            for (int j = 0; j < 8; j++)
                acc[j] += b2f((u16)v0[j]) + b2f((u16)v1[j]);
            k += 2;
        }
        if (k < e1) {
            unsigned i0 = (unsigned)csr[k];
            short8 v0 = *(const short8*)(hb + (size_t)i0 * O);
            #pragma unroll
            for (int j = 0; j < 8; j++) acc[j] += b2f((u16)v0[j]);
        }
        float dd = dinv[d];
        float outv[8];
        short8 res;
        #pragma unroll
        for (int j = 0; j < 8; j++) {
            outv[j] = lrelu(dd * acc[j] + b2f((u16)gv[j]));
            res[j] = (short)f2b(outv[j]);
        }
        *(short8*)(outp + (size_t)d * O + cof) = res;

        if constexpr (STATS) {
            float ss = 0.f;
            #pragma unroll
            for (int j = 0; j < 8; j++) ss += outv[j] * outv[j];
            ss += __shfl_xor(ss, 1); ss += __shfl_xor(ss, 2);
            ss += __shfl_xor(ss, 4); ss += __shfl_xor(ss, 8);
            float inv = 1.0f / fmaxf(sqrtf(ss), 1e-12f);
            if (c == 0) invn[d] = inv;
            #pragma unroll
            for (int j = 0; j < 8; j++) {
                float nv = outv[j] * inv;
                sreg[j] += nv; qreg[j] += nv * nv;
            }
        }
    }

    if constexpr (STATS) {
        __syncthreads();   // colS/colQ init visible
        #pragma unroll
        for (int j = 0; j < 8; j++) {
            float s = sreg[j];
            s += __shfl_xor(s, 16); s += __shfl_xor(s, 32);
            float qq = qreg[j];
            qq += __shfl_xor(qq, 16); qq += __shfl_xor(qq, 32);
            if ((t & 63) < 16) {
                atomicAdd(&colS[c * 8 + j], s);
                atomicAdd(&colQ[c * 8 + j], qq);
            }
        }
        __syncthreads();
        if (t < O) {
            float* rep = stA + (blockIdx.x & (SREP - 1)) * 512;
            atomicAdd(&rep[t], colS[t]);
            atomicAdd(&rep[256 + t], colQ[t]);
        }
    }
}

// ---------------------------------------------------------------------------
// Fused: depthwise 5x5 (SAME) on c[H,W,64] + concat with g3 -> linear 128->16
// -> softmax.  16x16 pixel tile + 2-halo, pixel-major LDS with stride 72.
// ---------------------------------------------------------------------------
__global__ __launch_bounds__(256) void final_fused(
        const u16* __restrict__ g3, const u16* __restrict__ cpre,
        const u16* __restrict__ dwW, const u16* __restrict__ db,
        const u16* __restrict__ lw, const u16* __restrict__ lb,
        const int* __restrict__ flag, void* __restrict__ outp) {
    __shared__ __align__(16) u16 tile[400 * 72];   // 57600 B
    __shared__ __align__(16) u16 wT[25 * 64];      // [tap][ch]
    __shared__ __align__(16) u16 wL[2048];         // [f][o]
    __shared__ float bDW[64];
    __shared__ float bL[16];
    int t = threadIdx.x;
    int tx = blockIdx.x % 24, ty = blockIdx.x / 24;
    int x0 = tx * 16 - 2, y0 = ty * 16 - 2;
    for (int i = t; i < 1600; i += 256) {
        int f = i / 25, tap = i - f * 25;
        wT[tap * 64 + f] = dwW[i];
    }
    for (int i = t; i < 2048; i += 256) wL[i] = lw[i];
    if (t < 64) bDW[t] = b2f(db[t]);
    if (t < 16) bL[t] = b2f(lb[t]);
    for (int u = t; u < 3200; u += 256) {
        int pix = u >> 3, c8 = u & 7;
        int gy = y0 + pix / 20, gx = x0 + pix % 20;
        short8 v = {0, 0, 0, 0, 0, 0, 0, 0};
        if (gy >= 0 && gy < HH && gx >= 0 && gx < WW)
            v = *(const short8*)(cpre + ((size_t)(gy * WW + gx)) * 64 + c8 * 8);
        *(short8*)&tile[pix * 72 + c8 * 8] = v;
    }
    __syncthreads();

    int px = t & 15, py = t >> 4;
    int node = (ty * 16 + py) * WW + tx * 16 + px;
    float y[16];
    #pragma unroll
    for (int o = 0; o < 16; o++) y[o] = bL[o];

    const u16* g3p = g3 + (size_t)node * 64;
    for (int c8 = 0; c8 < 8; c8++) {
        short8 gvv = *(const short8*)(g3p + c8 * 8);
        #pragma unroll
        for (int j = 0; j < 8; j++) {
            float g = b2f((u16)gvv[j]);
            const short8 w0 = *(const short8*)&wL[(c8 * 8 + j) * 16];
            const short8 w1 = *(const short8*)&wL[(c8 * 8 + j) * 16 + 8];
            #pragma unroll
            for (int o = 0; o < 8; o++) {
                y[o]     += g * b2f((u16)w0[o]);
                y[o + 8] += g * b2f((u16)w1[o]);
            }
        }
    }
    for (int c8 = 0; c8 < 8; c8++) {
        float acc[8] = {0.f, 0.f, 0.f, 0.f, 0.f, 0.f, 0.f, 0.f};
        #pragma unroll
        for (int dy = 0; dy < 5; dy++) {
            int rbase = ((py + dy) * 20 + px) * 72 + c8 * 8;
            #pragma unroll
            for (int dx = 0; dx < 5; dx++) {
                short8 v  = *(const short8*)&tile[rbase + dx * 72];
                short8 wv = *(const short8*)&wT[(dy * 5 + dx) * 64 + c8 * 8];
                #pragma unroll
                for (int j = 0; j < 8; j++)
                    acc[j] += b2f((u16)v[j]) * b2f((u16)wv[j]);
            }
        }
        #pragma unroll
        for (int j = 0; j < 8; j++) {
            float cv = lrelu(acc[j] + bDW[c8 * 8 + j]);
            int f = 64 + c8 * 8 + j;
            const short8 w0 = *(const short8*)&wL[f * 16];
            const short8 w1 = *(const short8*)&wL[f * 16 + 8];
            #pragma unroll
            for (int o = 0; o < 8; o++) {
                y[o]     += cv * b2f((u16)w0[o]);
                y[o + 8] += cv * b2f((u16)w1[o]);
            }
        }
    }
    float mx = y[0];
    #pragma unroll
    for (int o = 1; o < 16; o++) mx = fmaxf(mx, y[o]);
    float sum = 0.f;
    #pragma unroll
    for (int o = 0; o < 16; o++) { y[o] = __expf(y[o] - mx); sum += y[o]; }
    float inv = 1.0f / fmaxf(sum, 1e-30f);
    if (*flag) {
        float* of = (float*)outp;
        #pragma unroll
        for (int o = 0; o < 16; o++) of[(size_t)node * 16 + o] = y[o] * inv;
    } else {
        u16* oh = (u16*)outp;
        #pragma unroll
        for (int o = 0; o < 16; o++) oh[(size_t)node * 16 + o] = f2b(y[o] * inv);
    }
}

// ---------------------------------------------------------------------------
// Host launcher
// ---------------------------------------------------------------------------
extern "C" void kernel_launch(void* const* d_in, const int* in_sizes, int n_in,
                              void* d_out, int out_size, void* d_ws, size_t ws_size,
                              hipStream_t stream) {
    const void* X   = d_in[0];
    const int* EIDX = (const int*)d_in[1];
    const int* esrc = EIDX;
    const int* edst = EIDX + EE;

    char* ws = (char*)d_ws;
    size_t off = 0;
    auto alloc = [&](size_t sz) -> char* {
        size_t szr = (sz + 255) & ~(size_t)255;
        char* p;
        if (off + szr <= ws_size) { p = ws + off; off += szr; }
        else { p = ws; }
        return p;
    };

    int*   dflag   = (int*)alloc(256);
    static const int pidx[NPAR] = {2,3,4,5,6,7,8,9,10,11,12,13,14,
                                   15,16,17,18,19,20,21,22,23,24,25,26,27,28};
    static const int pn[NPAR]   = {200,200,25600,128,128,128,16384,128,
                                   128,128,8192,1600,64,
                                   128,128,16384,128,
                                   128,128,16384,128,
                                   128,128,8192,64,
                                   2048,16};
    u16* parena = (u16*)alloc(100352 * 2);
    PConv pc;
    {
        int po = 0;
        for (int i = 0; i < NPAR; i++) {
            pc.src[i] = d_in[pidx[i]];
            pc.n[i] = pn[i];
            pc.off[i] = po;
            po += (pn[i] + 15) & ~15;
        }
    }
    const u16* DN1G = parena + pc.off[0];
    const u16* DN1B = parena + pc.off[1];
    const u16* DNW1 = parena + pc.off[2];
    const u16* DNB1 = parena + pc.off[3];
    const u16* DN2G = parena + pc.off[4];
    const u16* DN2B = parena + pc.off[5];
    const u16* DNW2 = parena + pc.off[6];
    const u16* DNB2 = parena + pc.off[7];
    const u16* CBNG = parena + pc.off[8];
    const u16* CBNB = parena + pc.off[9];
    const u16* CPW  = parena + pc.off[10];
    const u16* CDW  = parena + pc.off[11];
    const u16* CDB  = parena + pc.off[12];
    const u16* G1G  = parena + pc.off[13];
    const u16* G1B  = parena + pc.off[14];
    const u16* G1W  = parena + pc.off[15];
    const u16* G1BI = parena + pc.off[16];
    const u16* G2G  = parena + pc.off[17];
    const u16* G2B  = parena + pc.off[18];
    const u16* G2W  = parena + pc.off[19];
    const u16* G2BI = parena + pc.off[20];
    const u16* G3G  = parena + pc.off[21];
    const u16* G3B  = parena + pc.off[22];
    const u16* G3W  = parena + pc.off[23];
    const u16* G3BI = parena + pc.off[24];
    const u16* LINW = parena + pc.off[25];
    const u16* LINB = parena + pc.off[26];

    // zero region (contiguous): arena + dbin + zpad
    float* arena   = (float*)alloc((size_t)6 * SLOTF * 4);
    int*   dbin    = (int*)alloc(DBINS * 4);
    u16*   zpad    = (u16*)alloc(256);
    // ---- end zero region ----
    int*   counts  = (int*)alloc((size_t)NBKT * NPBK * 4);
    int*   bbase   = (int*)alloc((NBKT + 1) * 4);
    int2*  bpair   = (int2*)alloc((size_t)EE * 8);
    int*   offv    = (int*)alloc((size_t)(NN + 1) * 4);
    int*   dbase   = (int*)alloc(DBINS * 4);
    int*   perm    = (int*)alloc((size_t)NN * 4);
    float* dinvp   = (float*)alloc((size_t)NN * 4);
    float* invnorm = (float*)alloc((size_t)NN * 4);
    u16*   W1T     = (u16*)alloc(128 * 224 * 2);
    u16*   W2T     = (u16*)alloc(128 * 128 * 2);
    u16*   WgT     = (u16*)alloc(192 * 128 * 2);   // 192 rows: GCN (128) + CNN pw (64)
    float* cb1     = (float*)alloc(128 * 4);
    float* cb2     = (float*)alloc(128 * 4);
    float* cbg     = (float*)alloc(192 * 4);
    int*   csr     = (int*)alloc((size_t)EE * 4);
    u16*   cbuf    = (u16*)alloc((size_t)NN * 64 * 2);    // CNN pre-dwconv "c"
    u16*   big1    = (u16*)alloc((size_t)NN * 128 * 2);   // h scratch
    u16*   big2    = (u16*)alloc((size_t)NN * 128 * 2);   // clean / g1 / g2 / g3

    const float invN = 1.0f / (float)NN;
    size_t zsz = (size_t)((char*)zpad + 256 - (char*)arena);
    size_t zcap = ((char*)arena >= ws && (size_t)((char*)arena - ws) < ws_size)
                      ? ws_size - (size_t)((char*)arena - ws) : 0;
    if (zsz > zcap) zsz = zcap;
    hipMemsetAsync(arena, 0, zsz, stream);

    // --- dtype detection + param conversion ---
    sniff<<<1, 256, 0, stream>>>((const u16*)X, dflag);
    convert_params<<<NPAR, 256, 0, stream>>>(pc, dflag, parena);

    // --- edge preprocessing: bucketed counting-sort CSR (no global atomics) ---
    count_bkt<<<NPBK, 256, 0, stream>>>(edst, counts);
    scan_bkt<<<1, 128, 0, stream>>>(counts, bbase);
    part_bkt<<<NPBK, 256, 0, stream>>>(esrc, edst, counts, bpair);
    csr_build<<<NBKT, 256, 0, stream>>>(bpair, bbase, offv, csr);
    mkdinv_deghist<<<NN / 256, 256, 0, stream>>>(offv, dinvp, dbin);
    deg_scan<<<1, 64, 0, stream>>>(dbin, dbase);
    deg_scatter<<<NN / 256, 256, 0, stream>>>(offv, dbase, perm);

    // --- denoise ---
    stats200<<<1152, 256, 0, stream>>>(X, dflag, arena + 0 * SLOTF);
    fold_bn<200, 224, 128><<<32, 256, 0, stream>>>(arena + 0 * SLOTF, invN, DN1G, DN1B, DNW1, DNB1, W1T, cb1);
    // dn1 gemm: fused column stats of big1 -> arena slot 1
    gemm_mfma<7, 200, 128, true, false, 1, false><<<NN / 64, 256, 0, stream>>>(
        X, W1T, cb1, nullptr, nullptr, dflag, big1, arena + 1 * SLOTF, nullptr, nullptr, nullptr, zpad);
    fold_bn<128, 128, 128><<<32, 256, 0, stream>>>(arena + 1 * SLOTF, invN, DN2G, DN2B, DNW2, DNB2, W2T, cb2);
    // dn2 gemm: fused clean-stats (slot 2, cnn BN), invnorm, normalized stats (slot 3, g1 BN)
    gemm_mfma<4, 128, 128, true, false, 2, false><<<NN / 64, 256, 0, stream>>>(
        big1, W2T, cb2, nullptr, nullptr, nullptr, big2, arena + 2 * SLOTF, arena + 3 * SLOTF, invnorm, nullptr, zpad);

    // --- GCN layer 1 + CNN pointwise fused (both read big2=clean) ---
    fold_bn<128, 128, 128><<<32, 256, 0, stream>>>(arena + 3 * SLOTF, invN, G1G, G1B, G1W, nullptr, WgT, cbg);
    fold_bn<128, 128, 64><<<16, 256, 0, stream>>>(arena + 2 * SLOTF, invN, CBNG, CBNB, CPW, nullptr,
                                                  WgT + 128 * 128, cbg + 128);
    // DUAL gemm: cols 0-127 -> big1 (GCN h2, scale epilogue), cols 128-191 -> cbuf (CNN c, leaky)
    gemm_mfma<4, 128, 192, false, true, 0, true><<<NN / 64, 256, 0, stream>>>(
        big2, WgT, cbg, invnorm, dinvp, nullptr, big1, nullptr, nullptr, nullptr, cbuf, zpad);
    // aggregate with fused rowstats (invnorm + normalized col stats -> slot 4)
    aggregate<128, 1, 4><<<NN / 64, 256, 0, stream>>>(
        big1, offv, csr, dinvp, G1BI, big2, arena + 4 * SLOTF, invnorm, perm);

    // --- GCN layer 2 ---
    fold_bn<128, 128, 128><<<32, 256, 0, stream>>>(arena + 4 * SLOTF, invN, G2G, G2B, G2W, nullptr, WgT, cbg);
    gemm_mfma<4, 128, 128, false, true, 0, false><<<NN / 64, 256, 0, stream>>>(
        big2, WgT, cbg, invnorm, dinvp, nullptr, big1, nullptr, nullptr, nullptr, nullptr, zpad);
    aggregate<128, 1, 4><<<NN / 64, 256, 0, stream>>>(
        big1, offv, csr, dinvp, G2BI, big2, arena + 5 * SLOTF, invnorm, perm);

    // --- GCN layer 3 (128 -> 64) ---
    fold_bn<128, 128, 64><<<16, 256, 0, stream>>>(arena + 5 * SLOTF, invN, G3G, G3B, G3W, nullptr, WgT, cbg);
    gemm_mfma<4, 128, 64, false, true, 0, false><<<NN / 64, 256, 0, stream>>>(
        big2, WgT, cbg, invnorm, dinvp, nullptr, big1, nullptr, nullptr, nullptr, nullptr, zpad);
    aggregate<64, 0, 1><<<NN / 32, 256, 0, stream>>>(
        big1, offv, csr, dinvp, G3BI, big2, nullptr, nullptr, perm);

    // --- fused dwconv + final linear + softmax ---
    final_fused<<<576, 256, 0, stream>>>(big2, cbuf, CDW, CDB, LINW, LINB, dflag, d_out);

    (void)in_sizes; (void)n_in; (void)out_size;
}

// Round 7
// 740.527 us; speedup vs baseline: 1.0785x; 1.0071x over previous
//
#include <hip/hip_runtime.h>
#include <stddef.h>

// ---------------------------------------------------------------------------
// Problem constants
// ---------------------------------------------------------------------------
#define HH 384
#define WW 384
#define CC 200
#define NN 147456      // HH*WW
#define EE 1179648
#define HIDE 128
#define COUT 64
#define NCLS 16
#define BN_EPS 1e-5f

// Replicated stat accumulators: R replicas of 512 floats per slot.
#define SREP 16
#define SLOTF (512 * SREP)
#define DBINS 64

// Bucketed CSR build
#define NBKT 72        // buckets of 2048 nodes (dst >> 11); 72*2048 = NN
#define NPBK 288       // partition blocks
#define EPB  4096      // edges per partition block; 288*4096 = EE

using u16 = unsigned short;
typedef __attribute__((ext_vector_type(8))) short short8;
typedef __attribute__((ext_vector_type(4))) float float4v;

__device__ __forceinline__ float b2f(u16 u) {
    union { unsigned int i; float f; } v; v.i = ((unsigned int)u) << 16; return v.f;
}
__device__ __forceinline__ u16 f2b(float f) {
    union { float f; unsigned int i; } v; v.f = f;
    unsigned int x = v.i;
    unsigned int r = (x + 0x7fffu + ((x >> 16) & 1u)) >> 16;   // RNE
    return (u16)r;
}
__device__ __forceinline__ float lrelu(float v) { return v > 0.f ? v : 0.01f * v; }

// global -> LDS direct DMA, 16B per lane.  LDS dest = uniform base + lane*16.
__device__ __forceinline__ void gload_lds16(const void* g, void* l) {
    __builtin_amdgcn_global_load_lds(
        (const __attribute__((address_space(1))) void*)g,
        (__attribute__((address_space(3))) void*)l, 16, 0, 0);
}

// ---------------------------------------------------------------------------
// Dtype sniffer: flag=1 means inputs are float32.
// ---------------------------------------------------------------------------
__global__ void sniff(const u16* __restrict__ x, int* __restrict__ flag) {
    __shared__ int cntS;
    if (threadIdx.x == 0) cntS = 0;
    __syncthreads();
    int c = 0;
    for (int i = 0; i < 8; i++) {
        u16 h = x[threadIdx.x * 8 + i];
        int hb = (h >> 8) & 0x7F;
        if (hb >= 0x3C && hb <= 0x41) c++;
    }
    atomicAdd(&cntS, c);
    __syncthreads();
    if (threadIdx.x == 0) *flag = (cntS < 1536) ? 1 : 0;
}

// ---------------------------------------------------------------------------
// Convert all float params into a bf16 arena (copy if already bf16).
// ---------------------------------------------------------------------------
#define NPAR 27
struct PConv { const void* src[NPAR]; int n[NPAR]; int off[NPAR]; };

__global__ void convert_params(PConv pc, const int* __restrict__ flag,
                               u16* __restrict__ dst) {
    int b = blockIdx.x;
    int n = pc.n[b];
    const void* s = pc.src[b];
    u16* d = dst + pc.off[b];
    int isf = *flag;
    if (isf) {
        const float* sf = (const float*)s;
        for (int i = threadIdx.x; i < n; i += 256) d[i] = f2b(sf[i]);
    } else {
        const u16* sh = (const u16*)s;
        for (int i = threadIdx.x; i < n; i += 256) d[i] = sh[i];
    }
}

// ---------------------------------------------------------------------------
// stats200: LDS-staged column stats of X[N,200] + bf16 conversion write-out
// (Xbf) when input is f32, so the dn1 GEMM can always take the DMA path.
// ---------------------------------------------------------------------------
__global__ __launch_bounds__(256) void stats200(const void* __restrict__ X,
                                                const int* __restrict__ flag,
                                                float* __restrict__ arena,
                                                u16* __restrict__ Xbf) {
    __shared__ __align__(16) u16 s[128 * 200];   // 51200 B
    int t = threadIdx.x;
    int r0 = blockIdx.x * 128;
    if (*flag) {
        const float* Xf = (const float*)X;
        for (int i = t; i < 128 * 25; i += 256) {
            int r = i / 25, kc = i - r * 25;
            const float* p = Xf + (size_t)(r0 + r) * CC + kc * 8;
            float4v a = *(const float4v*)p;
            float4v b = *(const float4v*)(p + 4);
            short8 v;
            #pragma unroll
            for (int j = 0; j < 4; j++) { v[j] = (short)f2b(a[j]); v[4 + j] = (short)f2b(b[j]); }
            *(short8*)&s[r * 200 + kc * 8] = v;
        }
        // write back the bf16 image (same index mapping -> no sync needed)
        for (int i = t; i < 128 * 25; i += 256) {
            int r = i / 25, kc = i - r * 25;
            *(short8*)(Xbf + (size_t)(r0 + r) * CC + kc * 8) =
                *(const short8*)&s[r * 200 + kc * 8];
        }
    } else {
        const u16* Xh = (const u16*)X;
        for (int i = t; i < 128 * 25; i += 256) {
            int r = i / 25, kc = i - r * 25;
            *(short8*)&s[r * 200 + kc * 8] =
                *(const short8*)(Xh + (size_t)(r0 + r) * CC + kc * 8);
        }
    }
    __syncthreads();
    if (t < CC) {
        float sum = 0.f, sq = 0.f;
        for (int r = 0; r < 128; r++) {
            float v = b2f(s[r * 200 + t]);
            sum += v; sq += v * v;
        }
        float* rep = arena + (blockIdx.x & (SREP - 1)) * 512;
        atomicAdd(&rep[t], sum);
        atomicAdd(&rep[256 + t], sq);
    }
}

// ---------------------------------------------------------------------------
// fold_bn body (device fn): sums SREP replicas, folds BN into W.
// ---------------------------------------------------------------------------
template<int K, int KPAD, int O>
__device__ __forceinline__ void fold_bn_body(
        const float* __restrict__ arena, float invN,
        const u16* __restrict__ bng, const u16* __restrict__ bnb,
        const u16* __restrict__ Wsrc, const u16* __restrict__ extrab,
        u16* __restrict__ WT, float* __restrict__ cb, int blk) {
    __shared__ float aS[KPAD], sS[KPAD];
    int t = threadIdx.x;
    if (t < KPAD) {
        float a = 0.f, sh = 0.f;
        if (t < K) {
            float sum = 0.f, sq = 0.f;
            #pragma unroll
            for (int r = 0; r < SREP; r++) {
                sum += arena[r * 512 + t];
                sq  += arena[r * 512 + 256 + t];
            }
            float m = sum * invN;
            float var = fmaxf(sq * invN - m * m, 0.f);
            a = b2f(bng[t]) * rsqrtf(var + BN_EPS);
            sh = b2f(bnb[t]) - m * a;
        }
        aS[t] = a; sS[t] = sh;
    }
    __syncthreads();
    int g = t >> 6, l = t & 63;
    int o = blk * 4 + g;
    if (o < O) {
        float c = 0.f;
        #pragma unroll
        for (int k = l; k < KPAD; k += 64) {
            float w = (k < K) ? b2f(Wsrc[k * O + o]) : 0.f;
            c += sS[k] * w;
            WT[o * KPAD + k] = f2b(aS[k] * w);
        }
        #pragma unroll
        for (int s = 32; s >= 1; s >>= 1) c += __shfl_down(c, s);
        if (l == 0) cb[o] = c + (extrab ? b2f(extrab[o]) : 0.f);
    }
}

template<int K, int KPAD, int O>
__global__ __launch_bounds__(256) void fold_bn(
        const float* __restrict__ arena, float invN,
        const u16* __restrict__ bng, const u16* __restrict__ bnb,
        const u16* __restrict__ Wsrc, const u16* __restrict__ extrab,
        u16* __restrict__ WT, float* __restrict__ cb) {
    fold_bn_body<K, KPAD, O>(arena, invN, bng, bnb, Wsrc, extrab, WT, cb,
                             blockIdx.x);
}

// Merged pair: blocks 0-31 fold the 128-out GCN weights, 32-47 the 64-out
// CNN pointwise weights (one dispatch instead of two).
__global__ __launch_bounds__(256) void fold_bn_pair(
        const float* __restrict__ arenaA, const float* __restrict__ arenaB,
        float invN,
        const u16* __restrict__ bngA, const u16* __restrict__ bnbA,
        const u16* __restrict__ WA, u16* __restrict__ WTA, float* __restrict__ cbA,
        const u16* __restrict__ bngB, const u16* __restrict__ bnbB,
        const u16* __restrict__ WB, u16* __restrict__ WTB, float* __restrict__ cbB) {
    if (blockIdx.x < 32)
        fold_bn_body<128, 128, 128>(arenaA, invN, bngA, bnbA, WA, nullptr,
                                    WTA, cbA, blockIdx.x);
    else
        fold_bn_body<128, 128, 64>(arenaB, invN, bngB, bnbB, WB, nullptr,
                                   WTB, cbB, blockIdx.x - 32);
}

// ---------------------------------------------------------------------------
// MFMA GEMM v6: always bf16 DMA staging (f32 inputs pre-converted to Abf by
// stats200).  Chunk-XOR swizzled LDS image via per-lane global address;
// fragment reads use the same XOR -> <=2-way bank aliasing.
// ---------------------------------------------------------------------------
template<int KT, int KSRC, int O, bool LEAKY, bool SCALE, int STATS, bool DUAL>
__global__ __launch_bounds__(256) void gemm_mfma(
        const void* __restrict__ Ap, const u16* __restrict__ Abf,
        const u16* __restrict__ WT,
        const float* __restrict__ cb, const float* __restrict__ s1,
        const float* __restrict__ s2, const int* __restrict__ f32p,
        u16* __restrict__ out, float* __restrict__ stA,
        float* __restrict__ stB, float* __restrict__ invn,
        u16* __restrict__ out2, const u16* __restrict__ zpad) {
    constexpr int KPAD = KT * 32;
    constexpr int CHD = KSRC / 8;               // real 16B chunks per row
    constexpr int ROWCH = ((KT * 4 + 7) / 8) * 8; // padded chunks (mult of 8)
    constexpr int ROWE = ROWCH * 8;             // elems per padded row
    constexpr int LPR = ROWCH;                  // lanes per row (16B each)
    constexpr int RPI = 64 / LPR;               // rows per 1024B DMA instr
    constexpr int NSI = 64 / RPI;               // DMA instrs per block
    constexpr int NCT = O / 16;
    constexpr int CPW = NCT / 4;                // column tiles per wave
    __shared__ __align__(16) u16 As[64 * ROWE];
    __shared__ float rS[4][64];
    __shared__ float invS[64];
    __shared__ float sS1[64], sS2[64];
    int tid = threadIdx.x;
    int row0 = blockIdx.x * 64;

    int isf = f32p ? *f32p : 0;
    const u16* A = isf ? Abf : (const u16*)Ap;
    {
        int l = tid & 63, wv = tid >> 6;
        int rl0 = l / LPR, cL = l - rl0 * LPR;
        #pragma unroll
        for (int s = 0; s < NSI / 4; s++) {
            int si = wv + s * 4;
            int rL = si * RPI + rl0;
            int chunk = cL ^ (rL & 7);
            const u16* src = (chunk < CHD)
                ? A + (size_t)(row0 + rL) * KSRC + chunk * 8 : zpad;
            gload_lds16(src, (char*)As + si * 1024);
        }
    }
    if (SCALE && tid < 64) { sS1[tid] = s1[row0 + tid]; sS2[tid] = s2[row0 + tid]; }
    __syncthreads();

    int w = tid >> 6, lane = tid & 63, m = lane & 15, q = lane >> 4;
    float4v acc[4][CPW];
    #pragma unroll
    for (int mf = 0; mf < 4; mf++)
        #pragma unroll
        for (int cp = 0; cp < CPW; cp++)
            acc[mf][cp] = (float4v){0.f, 0.f, 0.f, 0.f};

    const u16* Bbp = WT + (size_t)((w * CPW) * 16 + m) * KPAD + q * 8;

    #pragma unroll
    for (int kt = 0; kt < KT; kt++) {
        short8 af[4];
        int slot = (kt * 4 + q) ^ (m & 7);
        #pragma unroll
        for (int mf = 0; mf < 4; mf++)
            af[mf] = *(const short8*)&As[(size_t)(mf * 16 + m) * ROWE + slot * 8];
        #pragma unroll
        for (int cp = 0; cp < CPW; cp++) {
            short8 bf = *(const short8*)(Bbp + (size_t)cp * 16 * KPAD + kt * 32);
            #pragma unroll
            for (int mf = 0; mf < 4; mf++)
                acc[mf][cp] = __builtin_amdgcn_mfma_f32_16x16x32_bf16(
                    af[mf], bf, acc[mf][cp], 0, 0, 0);
        }
    }

    // ---- epilogue: apply, store, keep fp32 values in acc for stats ----
    float rp[4][4] = {};
    #pragma unroll
    for (int cp = 0; cp < CPW; cp++) {
        int ct = w * CPW + cp;
        int col = ct * 16 + m;
        float cbv = cb[col];
        #pragma unroll
        for (int mf = 0; mf < 4; mf++) {
            #pragma unroll
            for (int r = 0; r < 4; r++) {
                int rl = mf * 16 + q * 4 + r;
                float x = acc[mf][cp][r];
                if constexpr (DUAL) {
                    if (ct < 8) {
                        x = (x * sS1[rl] + cbv) * sS2[rl];
                        out[(size_t)(row0 + rl) * 128 + col] = f2b(x);
                    } else {
                        x = lrelu(x + cbv);
                        out2[(size_t)(row0 + rl) * 64 + (col - 128)] = f2b(x);
                    }
                } else {
                    if constexpr (SCALE) x = (x * sS1[rl] + cbv) * sS2[rl];
                    else                 x += cbv;
                    if constexpr (LEAKY) x = lrelu(x);
                    out[(size_t)(row0 + rl) * O + col] = f2b(x);
                }
                acc[mf][cp][r] = x;
                if constexpr (STATS == 2) rp[mf][r] += x * x;
            }
        }
    }

    if constexpr (STATS == 2) {
        #pragma unroll
        for (int mf = 0; mf < 4; mf++) {
            #pragma unroll
            for (int r = 0; r < 4; r++) {
                float v = rp[mf][r];
                v += __shfl_xor(v, 1); v += __shfl_xor(v, 2);
                v += __shfl_xor(v, 4); v += __shfl_xor(v, 8);
                if (m == 0) rS[w][mf * 16 + q * 4 + r] = v;
            }
        }
        __syncthreads();
        if (tid < 64) {
            float ss = rS[0][tid] + rS[1][tid] + rS[2][tid] + rS[3][tid];
            float inv = 1.0f / fmaxf(sqrtf(ss), 1e-12f);
            invS[tid] = inv;
            invn[row0 + tid] = inv;
        }
        __syncthreads();
    }

    if constexpr (STATS >= 1) {
        float* stAr = stA + (blockIdx.x & (SREP - 1)) * 512;
        float* stBr = (STATS == 2) ? stB + (blockIdx.x & (SREP - 1)) * 512 : nullptr;
        #pragma unroll
        for (int cp = 0; cp < CPW; cp++) {
            int col = (w * CPW + cp) * 16 + m;
            float cs = 0.f, cq = 0.f, ns = 0.f, nq = 0.f;
            #pragma unroll
            for (int mf = 0; mf < 4; mf++) {
                #pragma unroll
                for (int r = 0; r < 4; r++) {
                    float x = acc[mf][cp][r];
                    cs += x; cq += x * x;
                    if constexpr (STATS == 2) {
                        float nv = x * invS[mf * 16 + q * 4 + r];
                        ns += nv; nq += nv * nv;
                    }
                }
            }
            cs += __shfl_xor(cs, 16); cs += __shfl_xor(cs, 32);
            cq += __shfl_xor(cq, 16); cq += __shfl_xor(cq, 32);
            if constexpr (STATS == 2) {
                ns += __shfl_xor(ns, 16); ns += __shfl_xor(ns, 32);
                nq += __shfl_xor(nq, 16); nq += __shfl_xor(nq, 32);
            }
            if (q == 0) {
                atomicAdd(&stAr[col], cs);
                atomicAdd(&stAr[256 + col], cq);
                if constexpr (STATS == 2) {
                    atomicAdd(&stBr[col], ns);
                    atomicAdd(&stBr[256 + col], nq);
                }
            }
        }
    }
}

// ---------------------------------------------------------------------------
// Bucketed CSR build.  Bucket = dst >> 11 (72 buckets x 2048 nodes).
// part_bkt: block-local LDS bucket sort -> coalesced bpair writes.
// csr_build additionally emits dinv + degree histogram (counts already in LDS).
// ---------------------------------------------------------------------------
__global__ __launch_bounds__(256) void count_bkt(const int* __restrict__ edst,
                                                 int* __restrict__ counts) {
    __shared__ int h[NBKT];
    int t = threadIdx.x, blk = blockIdx.x;
    if (t < NBKT) h[t] = 0;
    __syncthreads();
    int base = blk * EPB;
    for (int i = t; i < EPB; i += 256) {
        unsigned d = (unsigned)edst[base + i];
        if (d < (unsigned)NN) atomicAdd(&h[d >> 11], 1);
    }
    __syncthreads();
    if (t < NBKT) counts[t * NPBK + blk] = h[t];
}

__global__ void scan_bkt(int* __restrict__ counts, int* __restrict__ bbase) {
    __shared__ int bs[NBKT], bb[NBKT];
    int t = threadIdx.x;
    if (t < NBKT) {
        int s = 0;
        for (int i = 0; i < NPBK; i++) s += counts[t * NPBK + i];
        bs[t] = s;
    }
    __syncthreads();
    if (t == 0) {
        int a = 0;
        for (int b = 0; b < NBKT; b++) { bb[b] = a; bbase[b] = a; a += bs[b]; }
        bbase[NBKT] = a;
    }
    __syncthreads();
    if (t < NBKT) {
        int run = bb[t];
        for (int i = 0; i < NPBK; i++) {
            int c = counts[t * NPBK + i];
            counts[t * NPBK + i] = run;
            run += c;
        }
    }
}

__global__ __launch_bounds__(256) void part_bkt(const int* __restrict__ esrc,
                                                const int* __restrict__ edst,
                                                const int* __restrict__ counts,
                                                int2* __restrict__ bpair) {
    __shared__ int2 buf[EPB];                // 32 KB
    __shared__ int lcnt[NBKT], lbase[NBKT], gbase[NBKT];
    int t = threadIdx.x, blk = blockIdx.x;
    if (t < NBKT) lcnt[t] = 0;
    __syncthreads();
    int base = blk * EPB;
    int dv[16], sv[16];
    #pragma unroll
    for (int j = 0; j < 16; j++) {
        dv[j] = edst[base + t + j * 256];
        sv[j] = esrc[base + t + j * 256];
        unsigned ud = (unsigned)dv[j];
        if (ud < (unsigned)NN) atomicAdd(&lcnt[ud >> 11], 1);
    }
    __syncthreads();
    if (t == 0) {
        int a = 0;
        for (int b = 0; b < NBKT; b++) { lbase[b] = a; a += lcnt[b]; }
    }
    __syncthreads();
    if (t < NBKT) { gbase[t] = counts[t * NPBK + blk]; lcnt[t] = 0; }
    __syncthreads();
    #pragma unroll
    for (int j = 0; j < 16; j++) {
        unsigned ud = (unsigned)dv[j];
        if (ud < (unsigned)NN) {
            int b = ud >> 11;
            int p = lbase[b] + atomicAdd(&lcnt[b], 1);
            int2 e; e.x = sv[j]; e.y = (int)ud;
            buf[p] = e;
        }
    }
    __syncthreads();
    int tot = lbase[NBKT - 1] + lcnt[NBKT - 1];
    for (int i = t; i < tot; i += 256) {
        int2 p = buf[i];
        int b = ((unsigned)p.y) >> 11;
        bpair[gbase[b] + (i - lbase[b])] = p;
    }
}

__global__ __launch_bounds__(256) void csr_build(const int2* __restrict__ bpair,
                                                 const int* __restrict__ bbase,
                                                 int* __restrict__ offv,
                                                 int* __restrict__ csr,
                                                 float* __restrict__ dinv,
                                                 int* __restrict__ dbin) {
    __shared__ int cntL[2048];
    __shared__ int exL[2048];
    __shared__ int tsum[256];
    __shared__ int hh[DBINS];
    int b = blockIdx.x, t = threadIdx.x;
    int e0 = bbase[b], e1 = bbase[b + 1];
    int n0 = b << 11;
    for (int i = t; i < 2048; i += 256) cntL[i] = 0;
    __syncthreads();
    for (int k = e0 + t; k < e1; k += 256) {
        int2 p = bpair[k];
        atomicAdd(&cntL[p.y & 2047], 1);
    }
    __syncthreads();
    int s = 0;
    #pragma unroll
    for (int j = 0; j < 8; j++) s += cntL[t * 8 + j];
    tsum[t] = s;
    __syncthreads();
    for (int o = 1; o < 256; o <<= 1) {
        int x = (t >= o) ? tsum[t - o] : 0;
        __syncthreads();
        tsum[t] += x;
        __syncthreads();
    }
    int run = tsum[t] - s;
    #pragma unroll
    for (int j = 0; j < 8; j++) { int c = cntL[t * 8 + j]; exL[t * 8 + j] = run; run += c; }
    __syncthreads();
    for (int i = t; i < 2048; i += 256) offv[n0 + i] = e0 + exL[i];
    if (b == NBKT - 1 && t == 0) offv[NN] = e1;
    for (int i = t; i < 2048; i += 256) cntL[i] = 0;
    if (t < DBINS) hh[t] = 0;
    __syncthreads();
    for (int k = e0 + t; k < e1; k += 256) {
        int2 p = bpair[k];
        int l = p.y & 2047;
        int pos = e0 + exL[l] + atomicAdd(&cntL[l], 1);
        csr[pos] = p.x;
    }
    __syncthreads();
    // cntL now holds per-node degrees again: emit dinv + degree histogram
    for (int i = t; i < 2048; i += 256) {
        int dg = cntL[i];
        dinv[n0 + i] = rsqrtf((float)dg + 1.0f);   // +1 self loop
        int dc = dg > DBINS - 1 ? DBINS - 1 : dg;
        atomicAdd(&hh[dc], 1);
    }
    __syncthreads();
    if (t < DBINS) atomicAdd(&dbin[t], hh[t]);
}

__global__ void deg_scan(const int* __restrict__ dbin, int* __restrict__ dbase) {
    if (threadIdx.x == 0) {
        int a = 0;
        for (int b = DBINS - 1; b >= 0; b--) { dbase[b] = a; a += dbin[b]; }
    }
}
__global__ void deg_scatter(const int* __restrict__ offv, int* __restrict__ dbase,
                            int* __restrict__ perm) {
    __shared__ int h[DBINS], base[DBINS];
    int t = threadIdx.x;
    if (t < DBINS) h[t] = 0;
    __syncthreads();
    int i = blockIdx.x * 256 + t;
    int dg = offv[i + 1] - offv[i];
    if (dg < 0) dg = 0; if (dg > DBINS - 1) dg = DBINS - 1;
    atomicAdd(&h[dg], 1);
    __syncthreads();
    if (t < DBINS) { base[t] = atomicAdd(&dbase[t], h[t]); h[t] = 0; }
    __syncthreads();
    int lp = atomicAdd(&h[dg], 1);
    perm[base[dg] + lp] = i;
}

// ---------------------------------------------------------------------------
// GCN aggregation (unchanged: perm + 8-deep unroll)
// ---------------------------------------------------------------------------
template<int O, int STATS, int GRP>
__global__ __launch_bounds__(256) void aggregate(
        const u16* __restrict__ h2, const int* __restrict__ offv,
        const int* __restrict__ csr, const float* __restrict__ dinv,
        const u16* __restrict__ gb, u16* __restrict__ outp,
        float* __restrict__ stA, float* __restrict__ invn,
        const int* __restrict__ perm) {
    constexpr int CH = O / 8;
    constexpr int NPB = 256 / CH;          // nodes per group
    __shared__ float colS[O], colQ[O];
    int t = threadIdx.x;
    if (STATS && t < O) { colS[t] = 0.f; colQ[t] = 0.f; }
    int local = t / CH, c = t % CH;
    size_t cof = (size_t)c * 8;
    const u16* hb = h2 + cof;
    short8 gv = *(const short8*)(gb + cof);
    float sreg[8] = {0.f, 0.f, 0.f, 0.f, 0.f, 0.f, 0.f, 0.f};
    float qreg[8] = {0.f, 0.f, 0.f, 0.f, 0.f, 0.f, 0.f, 0.f};

    #pragma unroll
    for (int g = 0; g < GRP; g++) {
        int pos = blockIdx.x * (NPB * GRP) + g * NPB + local;
        int d = perm[pos];
        float acc[8];
        short8 selfv = *(const short8*)(hb + (size_t)d * O);
        #pragma unroll
        for (int j = 0; j < 8; j++) acc[j] = b2f((u16)selfv[j]);
        int e0 = offv[d], e1 = offv[d + 1];
        if (e0 < 0) e0 = 0;
        if (e1 > EE) e1 = EE;
        int k = e0;
        for (; k + 8 <= e1; k += 8) {
            unsigned i0 = (unsigned)csr[k],     i1 = (unsigned)csr[k + 1];
            unsigned i2 = (unsigned)csr[k + 2], i3 = (unsigned)csr[k + 3];
            unsigned i4 = (unsigned)csr[k + 4], i5 = (unsigned)csr[k + 5];
            unsigned i6 = (unsigned)csr[k + 6], i7 = (unsigned)csr[k + 7];
            short8 v0 = *(const short8*)(hb + (size_t)i0 * O);
            short8 v1 = *(const short8*)(hb + (size_t)i1 * O);
            short8 v2 = *(const short8*)(hb + (size_t)i2 * O);
            short8 v3 = *(const short8*)(hb + (size_t)i3 * O);
            short8 v4 = *(const short8*)(hb + (size_t)i4 * O);
            short8 v5 = *(const short8*)(hb + (size_t)i5 * O);
            short8 v6 = *(const short8*)(hb + (size_t)i6 * O);
            short8 v7 = *(const short8*)(hb + (size_t)i7 * O);
            #pragma unroll
            for (int j = 0; j < 8; j++)
                acc[j] += ((b2f((u16)v0[j]) + b2f((u16)v1[j])) +
                           (b2f((u16)v2[j]) + b2f((u16)v3[j]))) +
                          ((b2f((u16)v4[j]) + b2f((u16)v5[j])) +
                           (b2f((u16)v6[j]) + b2f((u16)v7[j])));
        }
        if (k + 4 <= e1) {
            unsigned i0 = (unsigned)csr[k],     i1 = (unsigned)csr[k + 1];
            unsigned i2 = (unsigned)csr[k + 2], i3 = (unsigned)csr[k + 3];
            short8 v0 = *(const short8*)(hb + (size_t)i0 * O);
            short8 v1 = *(const short8*)(hb + (size_t)i1 * O);
            short8 v2 = *(const short8*)(hb + (size_t)i2 * O);
            short8 v3 = *(const short8*)(hb + (size_t)i3 * O);
            #pragma unroll
            for (int j = 0; j < 8; j++)
                acc[j] += (b2f((u16)v0[j]) + b2f((u16)v1[j])) +
                          (b2f((u16)v2[j]) + b2f((u16)v3[j]));
            k += 4;
        }
        if (k + 2 <= e1) {
            unsigned i0 = (unsigned)csr[k], i1 = (unsigned)csr[k + 1];
            short8 v0 = *(const short8*)(hb + (size_t)i0 * O);
            short8 v1 = *(const short8*)(hb + (size_t)i1 * O);
            #pragma unroll
            for (int j = 0; j < 8; j++)
                acc[j] += b2f((u16)v0[j]) + b2f((u16)v1[j]);
            k += 2;
        }
        if (k < e1) {
            unsigned i0 = (unsigned)csr[k];
            short8 v0 = *(const short8*)(hb + (size_t)i0 * O);
            #pragma unroll
            for (int j = 0; j < 8; j++) acc[j] += b2f((u16)v0[j]);
        }
        float dd = dinv[d];
        float outv[8];
        short8 res;
        #pragma unroll
        for (int j = 0; j < 8; j++) {
            outv[j] = lrelu(dd * acc[j] + b2f((u16)gv[j]));
            res[j] = (short)f2b(outv[j]);
        }
        *(short8*)(outp + (size_t)d * O + cof) = res;

        if constexpr (STATS) {
            float ss = 0.f;
            #pragma unroll
            for (int j = 0; j < 8; j++) ss += outv[j] * outv[j];
            ss += __shfl_xor(ss, 1); ss += __shfl_xor(ss, 2);
            ss += __shfl_xor(ss, 4); ss += __shfl_xor(ss, 8);
            float inv = 1.0f / fmaxf(sqrtf(ss), 1e-12f);
            if (c == 0) invn[d] = inv;
            #pragma unroll
            for (int j = 0; j < 8; j++) {
                float nv = outv[j] * inv;
                sreg[j] += nv; qreg[j] += nv * nv;
            }
        }
    }

    if constexpr (STATS) {
        __syncthreads();   // colS/colQ init visible
        #pragma unroll
        for (int j = 0; j < 8; j++) {
            float s = sreg[j];
            s += __shfl_xor(s, 16); s += __shfl_xor(s, 32);
            float qq = qreg[j];
            qq += __shfl_xor(qq, 16); qq += __shfl_xor(qq, 32);
            if ((t & 63) < 16) {
                atomicAdd(&colS[c * 8 + j], s);
                atomicAdd(&colQ[c * 8 + j], qq);
            }
        }
        __syncthreads();
        if (t < O) {
            float* rep = stA + (blockIdx.x & (SREP - 1)) * 512;
            atomicAdd(&rep[t], colS[t]);
            atomicAdd(&rep[256 + t], colQ[t]);
        }
    }
}

// ---------------------------------------------------------------------------
// Fused: depthwise 5x5 (SAME) on c[H,W,64] + concat with g3 -> linear 128->16
// -> softmax.  16x16 pixel tile + 2-halo, pixel-major LDS with stride 72.
// ---------------------------------------------------------------------------
__global__ __launch_bounds__(256) void final_fused(
        const u16* __restrict__ g3, const u16* __restrict__ cpre,
        const u16* __restrict__ dwW, const u16* __restrict__ db,
        const u16* __restrict__ lw, const u16* __restrict__ lb,
        const int* __restrict__ flag, void* __restrict__ outp) {
    __shared__ __align__(16) u16 tile[400 * 72];   // 57600 B
    __shared__ __align__(16) u16 wT[25 * 64];      // [tap][ch]
    __shared__ __align__(16) u16 wL[2048];         // [f][o]
    __shared__ float bDW[64];
    __shared__ float bL[16];
    int t = threadIdx.x;
    int tx = blockIdx.x % 24, ty = blockIdx.x / 24;
    int x0 = tx * 16 - 2, y0 = ty * 16 - 2;
    for (int i = t; i < 1600; i += 256) {
        int f = i / 25, tap = i - f * 25;
        wT[tap * 64 + f] = dwW[i];
    }
    for (int i = t; i < 2048; i += 256) wL[i] = lw[i];
    if (t < 64) bDW[t] = b2f(db[t]);
    if (t < 16) bL[t] = b2f(lb[t]);
    for (int u = t; u < 3200; u += 256) {
        int pix = u >> 3, c8 = u & 7;
        int gy = y0 + pix / 20, gx = x0 + pix % 20;
        short8 v = {0, 0, 0, 0, 0, 0, 0, 0};
        if (gy >= 0 && gy < HH && gx >= 0 && gx < WW)
            v = *(const short8*)(cpre + ((size_t)(gy * WW + gx)) * 64 + c8 * 8);
        *(short8*)&tile[pix * 72 + c8 * 8] = v;
    }
    __syncthreads();

    int px = t & 15, py = t >> 4;
    int node = (ty * 16 + py) * WW + tx * 16 + px;
    float y[16];
    #pragma unroll
    for (int o = 0; o < 16; o++) y[o] = bL[o];

    const u16* g3p = g3 + (size_t)node * 64;
    for (int c8 = 0; c8 < 8; c8++) {
        short8 gvv = *(const short8*)(g3p + c8 * 8);
        #pragma unroll
        for (int j = 0; j < 8; j++) {
            float g = b2f((u16)gvv[j]);
            const short8 w0 = *(const short8*)&wL[(c8 * 8 + j) * 16];
            const short8 w1 = *(const short8*)&wL[(c8 * 8 + j) * 16 + 8];
            #pragma unroll
            for (int o = 0; o < 8; o++) {
                y[o]     += g * b2f((u16)w0[o]);
                y[o + 8] += g * b2f((u16)w1[o]);
            }
        }
    }
    for (int c8 = 0; c8 < 8; c8++) {
        float acc[8] = {0.f, 0.f, 0.f, 0.f, 0.f, 0.f, 0.f, 0.f};
        #pragma unroll
        for (int dy = 0; dy < 5; dy++) {
            int rbase = ((py + dy) * 20 + px) * 72 + c8 * 8;
            #pragma unroll
            for (int dx = 0; dx < 5; dx++) {
                short8 v  = *(const short8*)&tile[rbase + dx * 72];
                short8 wv = *(const short8*)&wT[(dy * 5 + dx) * 64 + c8 * 8];
                #pragma unroll
                for (int j = 0; j < 8; j++)
                    acc[j] += b2f((u16)v[j]) * b2f((u16)wv[j]);
            }
        }
        #pragma unroll
        for (int j = 0; j < 8; j++) {
            float cv = lrelu(acc[j] + bDW[c8 * 8 + j]);
            int f = 64 + c8 * 8 + j;
            const short8 w0 = *(const short8*)&wL[f * 16];
            const short8 w1 = *(const short8*)&wL[f * 16 + 8];
            #pragma unroll
            for (int o = 0; o < 8; o++) {
                y[o]     += cv * b2f((u16)w0[o]);
                y[o + 8] += cv * b2f((u16)w1[o]);
            }
        }
    }
    float mx = y[0];
    #pragma unroll
    for (int o = 1; o < 16; o++) mx = fmaxf(mx, y[o]);
    float sum = 0.f;
    #pragma unroll
    for (int o = 0; o < 16; o++) { y[o] = __expf(y[o] - mx); sum += y[o]; }
    float inv = 1.0f / fmaxf(sum, 1e-30f);
    if (*flag) {
        float* of = (float*)outp;
        #pragma unroll
        for (int o = 0; o < 16; o++) of[(size_t)node * 16 + o] = y[o] * inv;
    } else {
        u16* oh = (u16*)outp;
        #pragma unroll
        for (int o = 0; o < 16; o++) oh[(size_t)node * 16 + o] = f2b(y[o] * inv);
    }
}

// ---------------------------------------------------------------------------
// Host launcher
// ---------------------------------------------------------------------------
extern "C" void kernel_launch(void* const* d_in, const int* in_sizes, int n_in,
                              void* d_out, int out_size, void* d_ws, size_t ws_size,
                              hipStream_t stream) {
    const void* X   = d_in[0];
    const int* EIDX = (const int*)d_in[1];
    const int* esrc = EIDX;
    const int* edst = EIDX + EE;

    char* ws = (char*)d_ws;
    size_t off = 0;
    auto alloc = [&](size_t sz) -> char* {
        size_t szr = (sz + 255) & ~(size_t)255;
        char* p;
        if (off + szr <= ws_size) { p = ws + off; off += szr; }
        else { p = ws; }
        return p;
    };

    int*   dflag   = (int*)alloc(256);
    static const int pidx[NPAR] = {2,3,4,5,6,7,8,9,10,11,12,13,14,
                                   15,16,17,18,19,20,21,22,23,24,25,26,27,28};
    static const int pn[NPAR]   = {200,200,25600,128,128,128,16384,128,
                                   128,128,8192,1600,64,
                                   128,128,16384,128,
                                   128,128,16384,128,
                                   128,128,8192,64,
                                   2048,16};
    u16* parena = (u16*)alloc(100352 * 2);
    PConv pc;
    {
        int po = 0;
        for (int i = 0; i < NPAR; i++) {
            pc.src[i] = d_in[pidx[i]];
            pc.n[i] = pn[i];
            pc.off[i] = po;
            po += (pn[i] + 15) & ~15;
        }
    }
    const u16* DN1G = parena + pc.off[0];
    const u16* DN1B = parena + pc.off[1];
    const u16* DNW1 = parena + pc.off[2];
    const u16* DNB1 = parena + pc.off[3];
    const u16* DN2G = parena + pc.off[4];
    const u16* DN2B = parena + pc.off[5];
    const u16* DNW2 = parena + pc.off[6];
    const u16* DNB2 = parena + pc.off[7];
    const u16* CBNG = parena + pc.off[8];
    const u16* CBNB = parena + pc.off[9];
    const u16* CPW  = parena + pc.off[10];
    const u16* CDW  = parena + pc.off[11];
    const u16* CDB  = parena + pc.off[12];
    const u16* G1G  = parena + pc.off[13];
    const u16* G1B  = parena + pc.off[14];
    const u16* G1W  = parena + pc.off[15];
    const u16* G1BI = parena + pc.off[16];
    const u16* G2G  = parena + pc.off[17];
    const u16* G2B  = parena + pc.off[18];
    const u16* G2W  = parena + pc.off[19];
    const u16* G2BI = parena + pc.off[20];
    const u16* G3G  = parena + pc.off[21];
    const u16* G3B  = parena + pc.off[22];
    const u16* G3W  = parena + pc.off[23];
    const u16* G3BI = parena + pc.off[24];
    const u16* LINW = parena + pc.off[25];
    const u16* LINB = parena + pc.off[26];

    // zero region (contiguous): arena + dbin + zpad
    float* arena   = (float*)alloc((size_t)6 * SLOTF * 4);
    int*   dbin    = (int*)alloc(DBINS * 4);
    u16*   zpad    = (u16*)alloc(256);
    // ---- end zero region ----
    int*   counts  = (int*)alloc((size_t)NBKT * NPBK * 4);
    int*   bbase   = (int*)alloc((NBKT + 1) * 4);
    int2*  bpair   = (int2*)alloc((size_t)EE * 8);
    int*   offv    = (int*)alloc((size_t)(NN + 1) * 4);
    int*   dbase   = (int*)alloc(DBINS * 4);
    int*   perm    = (int*)alloc((size_t)NN * 4);
    float* dinvp   = (float*)alloc((size_t)NN * 4);
    float* invnorm = (float*)alloc((size_t)NN * 4);
    u16*   W1T     = (u16*)alloc(128 * 224 * 2);
    u16*   W2T     = (u16*)alloc(128 * 128 * 2);
    u16*   WgT     = (u16*)alloc(192 * 128 * 2);   // 192 rows: GCN (128) + CNN pw (64)
    float* cb1     = (float*)alloc(128 * 4);
    float* cb2     = (float*)alloc(128 * 4);
    float* cbg     = (float*)alloc(192 * 4);
    int*   csr     = (int*)alloc((size_t)EE * 4);
    u16*   Xbf     = (u16*)alloc((size_t)NN * CC * 2);    // bf16 image of X (59 MB)
    u16*   cbuf    = (u16*)alloc((size_t)NN * 64 * 2);    // CNN pre-dwconv "c"
    u16*   big1    = (u16*)alloc((size_t)NN * 128 * 2);   // h scratch
    u16*   big2    = (u16*)alloc((size_t)NN * 128 * 2);   // clean / g1 / g2 / g3

    const float invN = 1.0f / (float)NN;
    size_t zsz = (size_t)((char*)zpad + 256 - (char*)arena);
    size_t zcap = ((char*)arena >= ws && (size_t)((char*)arena - ws) < ws_size)
                      ? ws_size - (size_t)((char*)arena - ws) : 0;
    if (zsz > zcap) zsz = zcap;
    hipMemsetAsync(arena, 0, zsz, stream);

    // --- dtype detection + param conversion ---
    sniff<<<1, 256, 0, stream>>>((const u16*)X, dflag);
    convert_params<<<NPAR, 256, 0, stream>>>(pc, dflag, parena);

    // --- edge preprocessing: bucketed counting-sort CSR (no global atomics) ---
    count_bkt<<<NPBK, 256, 0, stream>>>(edst, counts);
    scan_bkt<<<1, 128, 0, stream>>>(counts, bbase);
    part_bkt<<<NPBK, 256, 0, stream>>>(esrc, edst, counts, bpair);
    csr_build<<<NBKT, 256, 0, stream>>>(bpair, bbase, offv, csr, dinvp, dbin);
    deg_scan<<<1, 64, 0, stream>>>(dbin, dbase);
    deg_scatter<<<NN / 256, 256, 0, stream>>>(offv, dbase, perm);

    // --- denoise ---
    stats200<<<1152, 256, 0, stream>>>(X, dflag, arena + 0 * SLOTF, Xbf);
    fold_bn<200, 224, 128><<<32, 256, 0, stream>>>(arena + 0 * SLOTF, invN, DN1G, DN1B, DNW1, DNB1, W1T, cb1);
    // dn1 gemm: always bf16 DMA path (Xbf when f32 input); fused col stats -> slot 1
    gemm_mfma<7, 200, 128, true, false, 1, false><<<NN / 64, 256, 0, stream>>>(
        X, Xbf, W1T, cb1, nullptr, nullptr, dflag, big1, arena + 1 * SLOTF, nullptr, nullptr, nullptr, zpad);
    fold_bn<128, 128, 128><<<32, 256, 0, stream>>>(arena + 1 * SLOTF, invN, DN2G, DN2B, DNW2, DNB2, W2T, cb2);
    // dn2 gemm: fused clean-stats (slot 2, cnn BN), invnorm, normalized stats (slot 3, g1 BN)
    gemm_mfma<4, 128, 128, true, false, 2, false><<<NN / 64, 256, 0, stream>>>(
        big1, nullptr, W2T, cb2, nullptr, nullptr, nullptr, big2, arena + 2 * SLOTF, arena + 3 * SLOTF, invnorm, nullptr, zpad);

    // --- GCN layer 1 + CNN pointwise fused (both read big2=clean) ---
    fold_bn_pair<<<48, 256, 0, stream>>>(
        arena + 3 * SLOTF, arena + 2 * SLOTF, invN,
        G1G, G1B, G1W, WgT, cbg,
        CBNG, CBNB, CPW, WgT + 128 * 128, cbg + 128);
    // DUAL gemm: cols 0-127 -> big1 (GCN h2, scale epilogue), cols 128-191 -> cbuf (CNN c, leaky)
    gemm_mfma<4, 128, 192, false, true, 0, true><<<NN / 64, 256, 0, stream>>>(
        big2, nullptr, WgT, cbg, invnorm, dinvp, nullptr, big1, nullptr, nullptr, nullptr, cbuf, zpad);
    // aggregate with fused rowstats (invnorm + normalized col stats -> slot 4)
    aggregate<128, 1, 4><<<NN / 64, 256, 0, stream>>>(
        big1, offv, csr, dinvp, G1BI, big2, arena + 4 * SLOTF, invnorm, perm);

    // --- GCN layer 2 ---
    fold_bn<128, 128, 128><<<32, 256, 0, stream>>>(arena + 4 * SLOTF, invN, G2G, G2B, G2W, nullptr, WgT, cbg);
    gemm_mfma<4, 128, 128, false, true, 0, false><<<NN / 64, 256, 0, stream>>>(
        big2, nullptr, WgT, cbg, invnorm, dinvp, nullptr, big1, nullptr, nullptr, nullptr, nullptr, zpad);
    aggregate<128, 1, 4><<<NN / 64, 256, 0, stream>>>(
        big1, offv, csr, dinvp, G2BI, big2, arena + 5 * SLOTF, invnorm, perm);

    // --- GCN layer 3 (128 -> 64) ---
    fold_bn<128, 128, 64><<<16, 256, 0, stream>>>(arena + 5 * SLOTF, invN, G3G, G3B, G3W, nullptr, WgT, cbg);
    gemm_mfma<4, 128, 64, false, true, 0, false><<<NN / 64, 256, 0, stream>>>(
        big2, nullptr, WgT, cbg, invnorm, dinvp, nullptr, big1, nullptr, nullptr, nullptr, nullptr, zpad);
    aggregate<64, 0, 1><<<NN / 32, 256, 0, stream>>>(
        big1, offv, csr, dinvp, G3BI, big2, nullptr, nullptr, perm);

    // --- fused dwconv + final linear + softmax ---
    final_fused<<<576, 256, 0, stream>>>(big2, cbuf, CDW, CDB, LINW, LINB, dflag, d_out);

    (void)in_sizes; (void)n_in; (void)out_size;
}